// Round 19
// baseline (84.108 us; speedup 1.0000x reference)
//
#include <hip/hip_runtime.h>

typedef __attribute__((ext_vector_type(8))) short bf16x8;
typedef __attribute__((ext_vector_type(4))) float f32x4;
typedef __attribute__((ext_vector_type(2))) unsigned int u32x2;
typedef __attribute__((ext_vector_type(4))) unsigned int u32x4;

__device__ __forceinline__ unsigned short f2bf(float f) {
  return __builtin_bit_cast(unsigned short, (__bf16)f);
}
__device__ __forceinline__ unsigned pk2(float a, float b) {
  return (unsigned)f2bf(a) | ((unsigned)f2bf(b) << 16);
}
__device__ __forceinline__ float bf2f(unsigned short h) {
  unsigned u = ((unsigned)h) << 16;
  return __builtin_bit_cast(float, u);
}
__device__ __forceinline__ bf16x8 frag(u32x4 v) { return __builtin_bit_cast(bf16x8, v); }

#if __has_builtin(__builtin_amdgcn_exp2f)
#define EXP2(x) __builtin_amdgcn_exp2f(x)
#else
#define EXP2(x) exp2f(x)
#endif

__device__ __forceinline__ void wfence() {
  asm volatile("" ::: "memory");
  __builtin_amdgcn_wave_barrier();
}

#define MFMA16(a, b, c) __builtin_amdgcn_mfma_f32_16x16x32_bf16(a, b, c, 0, 0, 0)

#define LR 72
#define OFF_VT 4608
#define OFF_Q  9216
#define ZROW   13824
#define OFF_WST 13904                 // staged QKV chunks 0..23 (12288 ushorts)
#define LDS_TOT (13904 + 12288)       // 52,384 B -> 3 blocks/CU

// ws layout (ushort offsets): [0,49152) weight chunks; x2g (pi-packed bf16)
// at 65536. Needs ~33.7 MB of d_ws.
#define WS_X2 65536

// ---- weight prep (same mapping as R5..R18; 256-thread blocks, 4 chunks each) ----
__global__ void prep_weights(const float* __restrict__ wq, const float* __restrict__ wk,
                             const float* __restrict__ wv, const float* __restrict__ projw,
                             const float* __restrict__ fc1w, const float* __restrict__ fc2w,
                             unsigned short* __restrict__ ws) {
  int c = blockIdx.x * 4 + (threadIdx.x >> 6), l = threadIdx.x & 63;
  int g = l >> 4, jl = l & 15;
  int kind, T, ks;
  if (c < 8)       { kind = 0; T = c >> 1;        ks = c & 1; }
  else if (c < 16) { kind = 1; T = (c - 8) >> 1;  ks = (c - 8) & 1; }
  else if (c < 24) { kind = 2; T = (c - 16) >> 1; ks = (c - 16) & 1; }
  else if (c < 32) { kind = 3; T = (c - 24) >> 1; ks = (c - 24) & 1; }
  else if (c < 64) { kind = 4; T = (c - 32) >> 1; ks = (c - 32) & 1; }
  else             { kind = 5; T = (c - 64) >> 3; ks = (c - 64) & 7; }
  int n = 16 * T + jl;
  unsigned short* dst = ws + c * 512 + l * 8;
  #pragma unroll
  for (int jj = 0; jj < 8; ++jj) {
    int kp = 16 * (2 * (ks & 1) + (jj >> 2)) + 4 * g + (jj & 3);   // pi slot->col
    int kn = 32 * ks + 8 * g + jj;                                  // natural
    float v;
    if (kind == 0)      v = wq[(n >> 3) * 512 + kp * 8 + (n & 7)] * 0.18033688011f;
    else if (kind == 1) v = wk[(n >> 3) * 512 + kp * 8 + (n & 7)];
    else if (kind == 2) v = wv[(n >> 3) * 512 + kp * 8 + (n & 7)];
    else if (kind == 3) v = projw[kn * 64 + n];
    else if (kind == 4) v = fc1w[kp * 256 + n];
    else                v = fc2w[(64 * (ks >> 1) + kp) * 64 + n];
    dst[jj] = f2bf(v);
  }
}

// ========== K1: LN1 + QKV + attention + proj + residual (R18-validated) ==========
__global__ __launch_bounds__(256, 3) void block_attn(
    const float* __restrict__ x,
    const float* __restrict__ ln1w, const float* __restrict__ ln1b,
    const float* __restrict__ projb,
    unsigned short* __restrict__ wsm) {
  __shared__ __attribute__((aligned(16))) unsigned short lds[LDS_TOT];

  const int tid  = threadIdx.x;
  const int w    = tid >> 6;
  const int lane = tid & 63;
  const int g    = lane >> 4;
  const int jl   = lane & 15;
  const size_t b = blockIdx.x;
  const float* xb = x + b * 4096;
  const f32x4 zf = {0.f, 0.f, 0.f, 0.f};

  const int myrow = 16 * w + jl;
  const int krow  = myrow * LR;
  const int qrow  = OFF_Q + myrow * LR;
  const int sigb  = 32 * (w >> 1) + 8 * g + 4 * (w & 1);

  // ---- stage-issue: QKV weight chunks 0..23 (24 KB) ----
  const u32x4* wsrc = (const u32x4*)wsm;
  u32x4 stg0 = wsrc[0 * 256 + tid], stg1 = wsrc[1 * 256 + tid];
  u32x4 stg2 = wsrc[2 * 256 + tid], stg3 = wsrc[3 * 256 + tid];
  u32x4 stg4 = wsrc[4 * 256 + tid], stg5 = wsrc[5 * 256 + tid];

  // ---------- LN1 fully in registers (covers stage-load latency) ----------
  f32x4 xw[4];
  float mean, rstd;
  unsigned hr[8];
  {
    float s = 0.f, ss = 0.f;
    #pragma unroll
    for (int mi = 0; mi < 4; ++mi) {
      xw[mi] = *(const f32x4*)(xb + myrow * 64 + 16 * mi + 4 * g);
      #pragma unroll
      for (int r = 0; r < 4; ++r) { s += xw[mi][r]; ss += xw[mi][r] * xw[mi][r]; }
    }
    s  += __shfl_xor(s, 16, 64);  s  += __shfl_xor(s, 32, 64);
    ss += __shfl_xor(ss, 16, 64); ss += __shfl_xor(ss, 32, 64);
    mean = s * 0.015625f;
    rstd = rsqrtf(ss * 0.015625f - mean * mean + 1e-5f);
    #pragma unroll
    for (int mi = 0; mi < 4; ++mi) {
      f32x4 lw = *(const f32x4*)(ln1w + 16 * mi + 4 * g);
      f32x4 lb = *(const f32x4*)(ln1b + 16 * mi + 4 * g);
      float o0 = (xw[mi][0] - mean) * rstd * lw[0] + lb[0];
      float o1 = (xw[mi][1] - mean) * rstd * lw[1] + lb[1];
      float o2 = (xw[mi][2] - mean) * rstd * lw[2] + lb[2];
      float o3 = (xw[mi][3] - mean) * rstd * lw[3] + lb[3];
      hr[2 * mi] = pk2(o0, o1); hr[2 * mi + 1] = pk2(o2, o3);
    }
  }
  bf16x8 hb0 = frag((u32x4){hr[0], hr[1], hr[2], hr[3]});
  bf16x8 hb1 = frag((u32x4){hr[4], hr[5], hr[6], hr[7]});

  // ---- stage-write + zero row, then publish ----
  {
    u32x4* wdst = (u32x4*)(lds + OFF_WST);
    wdst[0 * 256 + tid] = stg0; wdst[1 * 256 + tid] = stg1;
    wdst[2 * 256 + tid] = stg2; wdst[3 * 256 + tid] = stg3;
    wdst[4 * 256 + tid] = stg4; wdst[5 * 256 + tid] = stg5;
  }
  if (tid < 40) ((unsigned*)(lds + ZROW))[tid] = 0u;
  __syncthreads();   // barrier 0: staged weights + zero row visible

  // ---------- QKV (rolled; weights from LDS) ----------
  #pragma clang loop unroll(disable)
  for (int mt = 0; mt < 4; ++mt) {
    const unsigned short* wq8 = lds + OFF_WST + (2 * mt) * 512 + lane * 8;
    bf16x8 aq0 = *(const bf16x8*)(wq8);
    bf16x8 aq1 = *(const bf16x8*)(wq8 + 512);
    bf16x8 ak0 = *(const bf16x8*)(wq8 + 8 * 512);
    bf16x8 ak1 = *(const bf16x8*)(wq8 + 9 * 512);
    bf16x8 bv0 = *(const bf16x8*)(wq8 + 16 * 512);
    bf16x8 bv1 = *(const bf16x8*)(wq8 + 17 * 512);
    f32x4 q = MFMA16(aq0, hb0, zf); q = MFMA16(aq1, hb1, q);
    *(u32x2*)(lds + qrow + 16 * mt + 4 * g) = (u32x2){pk2(q[0], q[1]), pk2(q[2], q[3])};
    f32x4 kk = MFMA16(ak0, hb0, zf); kk = MFMA16(ak1, hb1, kk);
    *(u32x2*)(lds + krow + 16 * mt + 4 * g) = (u32x2){pk2(kk[0], kk[1]), pk2(kk[2], kk[3])};
    f32x4 vv = MFMA16(hb0, bv0, zf); vv = MFMA16(hb1, bv1, vv);
    *(u32x2*)(lds + OFF_VT + (16 * mt + jl) * LR + sigb) =
        (u32x2){pk2(vv[0], vv[1]), pk2(vv[2], vv[3])};
  }
  __syncthreads();   // barrier 1: publish Q, K, VT

  // ---------- attention: wave w owns heads {2w, 2w+1} ----------
  {
    const bool g0 = (g == 0), j8 = (jl < 8);
    const int ka0 = g0 ? ((0  + jl) * LR) : ZROW;
    const int ka1 = g0 ? ((16 + jl) * LR) : ZROW;
    const int ka2 = g0 ? ((32 + jl) * LR) : ZROW;
    const int ka3 = g0 ? ((48 + jl) * LR) : ZROW;
    const int qb0 = g0 ? (OFF_Q + (0  + jl) * LR) : ZROW;
    const int qb1 = g0 ? (OFF_Q + (16 + jl) * LR) : ZROW;
    const int qb2 = g0 ? (OFF_Q + (32 + jl) * LR) : ZROW;
    const int qb3 = g0 ? (OFF_Q + (48 + jl) * LR) : ZROW;
    const bool m0 = (4 * g + 0 <= jl), m1 = (4 * g + 1 <= jl);
    const bool m2 = (4 * g + 2 <= jl), m3 = (4 * g + 3 <= jl);
    #pragma clang loop unroll(disable)
    for (int hh = 0; hh < 2; ++hh) {
      const int ho = 16 * w + 8 * hh;
      const int vbase = j8 ? (OFF_VT + (ho + jl) * LR) : ZROW;
      bf16x8 bq0 = *(const bf16x8*)(lds + qb0 + ho);
      bf16x8 bq1 = *(const bf16x8*)(lds + qb1 + ho);
      bf16x8 bq2 = *(const bf16x8*)(lds + qb2 + ho);
      bf16x8 bq3 = *(const bf16x8*)(lds + qb3 + ho);
      bf16x8 k0  = *(const bf16x8*)(lds + ka0 + ho);
      bf16x8 k1  = *(const bf16x8*)(lds + ka1 + ho);
      bf16x8 k2  = *(const bf16x8*)(lds + ka2 + ho);
      bf16x8 k3  = *(const bf16x8*)(lds + ka3 + ho);
      bf16x8 aw0 = *(const bf16x8*)(lds + vbase + 8 * g);
      bf16x8 aw1 = *(const bf16x8*)(lds + vbase + 32 + 8 * g);
      wfence();
      f32x4 s00 = MFMA16(k0, bq0, zf);
      f32x4 s10 = MFMA16(k0, bq1, zf);
      f32x4 s11 = MFMA16(k1, bq1, zf);
      {   // qt 0
        float e0 = m0 ? EXP2(s00[0]) : 0.f, e1 = m1 ? EXP2(s00[1]) : 0.f;
        float e2 = m2 ? EXP2(s00[2]) : 0.f, e3 = m3 ? EXP2(s00[3]) : 0.f;
        float sum = (e0 + e1) + (e2 + e3);
        sum += __shfl_xor(sum, 16, 64); sum += __shfl_xor(sum, 32, 64);
        float inv = __builtin_amdgcn_rcpf(sum);
        bf16x8 bp0 = frag((u32x4){pk2(e0, e1), pk2(e2, e3), 0u, 0u});
        f32x4 pv = MFMA16(aw0, bp0, zf);
        if (g < 2)
          *(u32x2*)(lds + OFF_Q + jl * LR + ho + 4 * g) =
              (u32x2){pk2(pv[0] * inv, pv[1] * inv), pk2(pv[2] * inv, pv[3] * inv)};
      }
      {   // qt 1
        float a0 = EXP2(s10[0]), a1 = EXP2(s10[1]);
        float a2 = EXP2(s10[2]), a3 = EXP2(s10[3]);
        float e0 = m0 ? EXP2(s11[0]) : 0.f, e1 = m1 ? EXP2(s11[1]) : 0.f;
        float e2 = m2 ? EXP2(s11[2]) : 0.f, e3 = m3 ? EXP2(s11[3]) : 0.f;
        float sum = ((a0 + a1) + (a2 + a3)) + ((e0 + e1) + (e2 + e3));
        sum += __shfl_xor(sum, 16, 64); sum += __shfl_xor(sum, 32, 64);
        float inv = __builtin_amdgcn_rcpf(sum);
        bf16x8 bp0 = frag((u32x4){pk2(a0, a1), pk2(a2, a3), pk2(e0, e1), pk2(e2, e3)});
        f32x4 pv = MFMA16(aw0, bp0, zf);
        if (g < 2)
          *(u32x2*)(lds + OFF_Q + (16 + jl) * LR + ho + 4 * g) =
              (u32x2){pk2(pv[0] * inv, pv[1] * inv), pk2(pv[2] * inv, pv[3] * inv)};
      }
      f32x4 s20 = MFMA16(k0, bq2, zf);
      f32x4 s21 = MFMA16(k1, bq2, zf);
      f32x4 s22 = MFMA16(k2, bq2, zf);
      f32x4 s30 = MFMA16(k0, bq3, zf);
      f32x4 s31 = MFMA16(k1, bq3, zf);
      f32x4 s32 = MFMA16(k2, bq3, zf);
      f32x4 s33 = MFMA16(k3, bq3, zf);
      {   // qt 2
        float a0 = EXP2(s20[0]), a1 = EXP2(s20[1]);
        float a2 = EXP2(s20[2]), a3 = EXP2(s20[3]);
        float c0 = EXP2(s21[0]), c1 = EXP2(s21[1]);
        float c2 = EXP2(s21[2]), c3 = EXP2(s21[3]);
        float e0 = m0 ? EXP2(s22[0]) : 0.f, e1 = m1 ? EXP2(s22[1]) : 0.f;
        float e2 = m2 ? EXP2(s22[2]) : 0.f, e3 = m3 ? EXP2(s22[3]) : 0.f;
        float sum = ((a0 + a1) + (a2 + a3)) + ((c0 + c1) + (c2 + c3))
                  + ((e0 + e1) + (e2 + e3));
        sum += __shfl_xor(sum, 16, 64); sum += __shfl_xor(sum, 32, 64);
        float inv = __builtin_amdgcn_rcpf(sum);
        bf16x8 bp0 = frag((u32x4){pk2(a0, a1), pk2(a2, a3), pk2(c0, c1), pk2(c2, c3)});
        bf16x8 bp1 = frag((u32x4){pk2(e0, e1), pk2(e2, e3), 0u, 0u});
        f32x4 pv = MFMA16(aw0, bp0, zf); pv = MFMA16(aw1, bp1, pv);
        if (g < 2)
          *(u32x2*)(lds + OFF_Q + (32 + jl) * LR + ho + 4 * g) =
              (u32x2){pk2(pv[0] * inv, pv[1] * inv), pk2(pv[2] * inv, pv[3] * inv)};
      }
      {   // qt 3
        float a0 = EXP2(s30[0]), a1 = EXP2(s30[1]);
        float a2 = EXP2(s30[2]), a3 = EXP2(s30[3]);
        float c0 = EXP2(s31[0]), c1 = EXP2(s31[1]);
        float c2 = EXP2(s31[2]), c3 = EXP2(s31[3]);
        float d0 = EXP2(s32[0]), d1 = EXP2(s32[1]);
        float d2 = EXP2(s32[2]), d3 = EXP2(s32[3]);
        float e0 = m0 ? EXP2(s33[0]) : 0.f, e1 = m1 ? EXP2(s33[1]) : 0.f;
        float e2 = m2 ? EXP2(s33[2]) : 0.f, e3 = m3 ? EXP2(s33[3]) : 0.f;
        float sum = ((a0 + a1) + (a2 + a3)) + ((c0 + c1) + (c2 + c3))
                  + ((d0 + d1) + (d2 + d3)) + ((e0 + e1) + (e2 + e3));
        sum += __shfl_xor(sum, 16, 64); sum += __shfl_xor(sum, 32, 64);
        float inv = __builtin_amdgcn_rcpf(sum);
        bf16x8 bp0 = frag((u32x4){pk2(a0, a1), pk2(a2, a3), pk2(c0, c1), pk2(c2, c3)});
        bf16x8 bp1 = frag((u32x4){pk2(d0, d1), pk2(d2, d3), pk2(e0, e1), pk2(e2, e3)});
        f32x4 pv = MFMA16(aw0, bp0, zf); pv = MFMA16(aw1, bp1, pv);
        if (g < 2)
          *(u32x2*)(lds + OFF_Q + (48 + jl) * LR + ho + 4 * g) =
              (u32x2){pk2(pv[0] * inv, pv[1] * inv), pk2(pv[2] * inv, pv[3] * inv)};
      }
    }
  }
  __syncthreads();   // barrier 2: publish attn
  bf16x8 bat0 = *(const bf16x8*)(lds + qrow + 8 * g);
  bf16x8 bat1 = *(const bf16x8*)(lds + qrow + 32 + 8 * g);

  // ---------- proj + residual; store x2 pi-packed (ONLY output of K1) ----------
  {
    unsigned short* xrow = wsm + WS_X2 + (b * 64 + (size_t)myrow) * 64;
    f32x4 x20, x21, x22, x23;
    {
      bf16x8 a0 = *(const bf16x8*)(wsm + 24 * 512 + lane * 8);
      bf16x8 a1 = *(const bf16x8*)(wsm + 25 * 512 + lane * 8);
      f32x4 acc = MFMA16(a0, bat0, zf); acc = MFMA16(a1, bat1, acc);
      x20 = xw[0] + acc + *(const f32x4*)(projb + 4 * g);
    }
    {
      bf16x8 a0 = *(const bf16x8*)(wsm + 26 * 512 + lane * 8);
      bf16x8 a1 = *(const bf16x8*)(wsm + 27 * 512 + lane * 8);
      f32x4 acc = MFMA16(a0, bat0, zf); acc = MFMA16(a1, bat1, acc);
      x21 = xw[1] + acc + *(const f32x4*)(projb + 16 + 4 * g);
    }
    *(u32x4*)(xrow + 8 * g) = (u32x4){pk2(x20[0], x20[1]), pk2(x20[2], x20[3]),
                                      pk2(x21[0], x21[1]), pk2(x21[2], x21[3])};
    {
      bf16x8 a0 = *(const bf16x8*)(wsm + 28 * 512 + lane * 8);
      bf16x8 a1 = *(const bf16x8*)(wsm + 29 * 512 + lane * 8);
      f32x4 acc = MFMA16(a0, bat0, zf); acc = MFMA16(a1, bat1, acc);
      x22 = xw[2] + acc + *(const f32x4*)(projb + 32 + 4 * g);
    }
    {
      bf16x8 a0 = *(const bf16x8*)(wsm + 30 * 512 + lane * 8);
      bf16x8 a1 = *(const bf16x8*)(wsm + 31 * 512 + lane * 8);
      f32x4 acc = MFMA16(a0, bat0, zf); acc = MFMA16(a1, bat1, acc);
      x23 = xw[3] + acc + *(const f32x4*)(projb + 48 + 4 * g);
    }
    *(u32x4*)(xrow + 32 + 8 * g) = (u32x4){pk2(x22[0], x22[1]), pk2(x22[2], x22[3]),
                                           pk2(x23[0], x23[1]), pk2(x23[2], x23[3])};
  }
}

// ========== K2: LN2 + FF GEMM -- 512 threads, 8 waves share one weight stage ==========
__global__ __launch_bounds__(512, 4) void ff_stream(
    const unsigned short* __restrict__ wsm,
    const float* __restrict__ ln2w, const float* __restrict__ ln2b,
    const float* __restrict__ fc1b, const float* __restrict__ fc2b,
    float* __restrict__ out) {
  __shared__ __attribute__((aligned(16))) unsigned short ldsw[32768];  // 64 KB

  const int tid  = threadIdx.x;
  const int w    = tid >> 6;        // 8 waves; each wave owns 16 tokens per pass
  const int lane = tid & 63;
  const int g    = lane >> 4;
  const int jl   = lane & 15;
  const f32x4 zf = {0.f, 0.f, 0.f, 0.f};

  // stage fc1+fc2 chunks (orig 32..96 -> local 0..64): 64 KB coalesced
  {
    const u32x4* src = (const u32x4*)(wsm + 16384);
    u32x4* dst = (u32x4*)ldsw;
    #pragma unroll
    for (int k = 0; k < 8; ++k) dst[k * 512 + tid] = src[k * 512 + tid];
  }
  __syncthreads();

  // LN2 scales + fc2 bias (hoisted; L2-hot)
  f32x4 lw2[4], lb2[4], fb2[4];
  #pragma unroll
  for (int mi = 0; mi < 4; ++mi) {
    lw2[mi] = *(const f32x4*)(ln2w + 16 * mi + 4 * g);
    lb2[mi] = *(const f32x4*)(ln2b + 16 * mi + 4 * g);
    fb2[mi] = *(const f32x4*)(fc2b + 16 * mi + 4 * g);
  }

  const unsigned short* x2g = wsm + WS_X2;

  #pragma clang loop unroll(disable)
  for (int p = 0; p < 4; ++p) {
    // block covers 128 tokens per pass (8 waves x 16 tokens)
    const size_t t = (size_t)blockIdx.x * 512 + p * 128 + w * 16 + jl;
    const unsigned short* xrow = x2g + t * 64;
    u32x4 v0 = *(const u32x4*)(xrow + 8 * g);
    u32x4 v1 = *(const u32x4*)(xrow + 32 + 8 * g);
    f32x4 x2[4];
    #pragma unroll
    for (int q = 0; q < 2; ++q) {
      u32x4 vv = q ? v1 : v0;
      x2[2 * q + 0][0] = bf2f((unsigned short)(vv[0] & 0xFFFF));
      x2[2 * q + 0][1] = bf2f((unsigned short)(vv[0] >> 16));
      x2[2 * q + 0][2] = bf2f((unsigned short)(vv[1] & 0xFFFF));
      x2[2 * q + 0][3] = bf2f((unsigned short)(vv[1] >> 16));
      x2[2 * q + 1][0] = bf2f((unsigned short)(vv[2] & 0xFFFF));
      x2[2 * q + 1][1] = bf2f((unsigned short)(vv[2] >> 16));
      x2[2 * q + 1][2] = bf2f((unsigned short)(vv[3] & 0xFFFF));
      x2[2 * q + 1][3] = bf2f((unsigned short)(vv[3] >> 16));
    }
    // LN2 in registers
    float s = 0.f, ss = 0.f;
    #pragma unroll
    for (int mi = 0; mi < 4; ++mi)
      #pragma unroll
      for (int r = 0; r < 4; ++r) { s += x2[mi][r]; ss += x2[mi][r] * x2[mi][r]; }
    s  += __shfl_xor(s, 16, 64);  s  += __shfl_xor(s, 32, 64);
    ss += __shfl_xor(ss, 16, 64); ss += __shfl_xor(ss, 32, 64);
    float mean2 = s * 0.015625f;
    float rstd2 = rsqrtf(ss * 0.015625f - mean2 * mean2 + 1e-5f);
    unsigned h2[8];
    #pragma unroll
    for (int mi = 0; mi < 4; ++mi) {
      float o0 = (x2[mi][0] - mean2) * rstd2 * lw2[mi][0] + lb2[mi][0];
      float o1 = (x2[mi][1] - mean2) * rstd2 * lw2[mi][1] + lb2[mi][1];
      float o2 = (x2[mi][2] - mean2) * rstd2 * lw2[mi][2] + lb2[mi][2];
      float o3 = (x2[mi][3] - mean2) * rstd2 * lw2[mi][3] + lb2[mi][3];
      h2[2 * mi] = pk2(o0, o1); h2[2 * mi + 1] = pk2(o2, o3);
    }
    bf16x8 hc0 = frag((u32x4){h2[0], h2[1], h2[2], h2[3]});
    bf16x8 hc1 = frag((u32x4){h2[4], h2[5], h2[6], h2[7]});

    f32x4 acc2[4];
    #pragma unroll
    for (int mi = 0; mi < 4; ++mi) acc2[mi] = zf;
    #pragma clang loop unroll(disable)
    for (int c = 0; c < 4; ++c) {
      const unsigned short* w1c = ldsw + (8 * c) * 512 + lane * 8;
      const unsigned short* w2c = ldsw + (32 + 2 * c) * 512 + lane * 8;
      const float* b1c = fc1b + 64 * c + 4 * g;
      unsigned fr0, fr1, fr2, fr3, fr4, fr5, fr6, fr7;
      {
        bf16x8 a0 = *(const bf16x8*)(w1c);
        bf16x8 a1 = *(const bf16x8*)(w1c + 512);
        f32x4 acc = MFMA16(a0, hc0, zf); acc = MFMA16(a1, hc1, acc);
        f32x4 bb = *(const f32x4*)(b1c);
        fr0 = pk2(fmaxf(acc[0] + bb[0], 0.f), fmaxf(acc[1] + bb[1], 0.f));
        fr1 = pk2(fmaxf(acc[2] + bb[2], 0.f), fmaxf(acc[3] + bb[3], 0.f));
      }
      {
        bf16x8 a0 = *(const bf16x8*)(w1c + 2 * 512);
        bf16x8 a1 = *(const bf16x8*)(w1c + 3 * 512);
        f32x4 acc = MFMA16(a0, hc0, zf); acc = MFMA16(a1, hc1, acc);
        f32x4 bb = *(const f32x4*)(b1c + 16);
        fr2 = pk2(fmaxf(acc[0] + bb[0], 0.f), fmaxf(acc[1] + bb[1], 0.f));
        fr3 = pk2(fmaxf(acc[2] + bb[2], 0.f), fmaxf(acc[3] + bb[3], 0.f));
      }
      {
        bf16x8 a0 = *(const bf16x8*)(w1c + 4 * 512);
        bf16x8 a1 = *(const bf16x8*)(w1c + 5 * 512);
        f32x4 acc = MFMA16(a0, hc0, zf); acc = MFMA16(a1, hc1, acc);
        f32x4 bb = *(const f32x4*)(b1c + 32);
        fr4 = pk2(fmaxf(acc[0] + bb[0], 0.f), fmaxf(acc[1] + bb[1], 0.f));
        fr5 = pk2(fmaxf(acc[2] + bb[2], 0.f), fmaxf(acc[3] + bb[3], 0.f));
      }
      {
        bf16x8 a0 = *(const bf16x8*)(w1c + 6 * 512);
        bf16x8 a1 = *(const bf16x8*)(w1c + 7 * 512);
        f32x4 acc = MFMA16(a0, hc0, zf); acc = MFMA16(a1, hc1, acc);
        f32x4 bb = *(const f32x4*)(b1c + 48);
        fr6 = pk2(fmaxf(acc[0] + bb[0], 0.f), fmaxf(acc[1] + bb[1], 0.f));
        fr7 = pk2(fmaxf(acc[2] + bb[2], 0.f), fmaxf(acc[3] + bb[3], 0.f));
      }
      bf16x8 bf0 = frag((u32x4){fr0, fr1, fr2, fr3});
      bf16x8 bf1 = frag((u32x4){fr4, fr5, fr6, fr7});
      #pragma unroll
      for (int mi = 0; mi < 4; ++mi) {
        bf16x8 w20 = *(const bf16x8*)(w2c + (8 * mi) * 512);
        bf16x8 w21 = *(const bf16x8*)(w2c + (8 * mi + 1) * 512);
        acc2[mi] = MFMA16(w20, bf0, acc2[mi]);
        acc2[mi] = MFMA16(w21, bf1, acc2[mi]);
      }
    }
    float* ob = out + t * 64;
    #pragma unroll
    for (int mi = 0; mi < 4; ++mi) {
      f32x4 o = x2[mi] + acc2[mi] + fb2[mi];
      *(f32x4*)(ob + 16 * mi + 4 * g) = o;
    }
  }
}

extern "C" void kernel_launch(void* const* d_in, const int* in_sizes, int n_in,
                              void* d_out, int out_size, void* d_ws, size_t ws_size,
                              hipStream_t stream) {
  const float* x     = (const float*)d_in[0];
  const float* ln1w  = (const float*)d_in[1];
  const float* ln1b  = (const float*)d_in[2];
  const float* wq    = (const float*)d_in[3];
  const float* wk    = (const float*)d_in[4];
  const float* wvp   = (const float*)d_in[5];
  const float* projw = (const float*)d_in[6];
  const float* projb = (const float*)d_in[7];
  const float* ln2w  = (const float*)d_in[8];
  const float* ln2b  = (const float*)d_in[9];
  const float* fc1w  = (const float*)d_in[10];
  const float* fc1b  = (const float*)d_in[11];
  const float* fc2w  = (const float*)d_in[12];
  const float* fc2b  = (const float*)d_in[13];
  unsigned short* ws = (unsigned short*)d_ws;   // needs ~33.7 MB
  float* out = (float*)d_out;

  prep_weights<<<dim3(24), dim3(256), 0, stream>>>(wq, wk, wvp, projw, fc1w, fc2w, ws);

  int nblk = in_sizes[0] / 4096;
  block_attn<<<dim3(nblk), dim3(256), 0, stream>>>(
      x, ln1w, ln1b, projb, ws);

  int nblk2 = (nblk * 64) / 512;   // 512 tokens per FF block (128/pass x 4)
  ff_stream<<<dim3(nblk2), dim3(512), 0, stream>>>(ws, ln2w, ln2b, fc1b, fc2b, out);
}

// Round 20
// 83.921 us; speedup vs baseline: 1.0022x; 1.0022x over previous
//
#include <hip/hip_runtime.h>

typedef __attribute__((ext_vector_type(8))) short bf16x8;
typedef __attribute__((ext_vector_type(4))) float f32x4;
typedef __attribute__((ext_vector_type(2))) unsigned int u32x2;
typedef __attribute__((ext_vector_type(4))) unsigned int u32x4;

__device__ __forceinline__ unsigned short f2bf(float f) {
  return __builtin_bit_cast(unsigned short, (__bf16)f);
}
__device__ __forceinline__ unsigned pk2(float a, float b) {
  return (unsigned)f2bf(a) | ((unsigned)f2bf(b) << 16);
}
__device__ __forceinline__ float bf2f(unsigned short h) {
  unsigned u = ((unsigned)h) << 16;
  return __builtin_bit_cast(float, u);
}
__device__ __forceinline__ bf16x8 frag(u32x4 v) { return __builtin_bit_cast(bf16x8, v); }

#if __has_builtin(__builtin_amdgcn_exp2f)
#define EXP2(x) __builtin_amdgcn_exp2f(x)
#else
#define EXP2(x) exp2f(x)
#endif

__device__ __forceinline__ void wfence() {
  asm volatile("" ::: "memory");
  __builtin_amdgcn_wave_barrier();
}

#define MFMA16(a, b, c) __builtin_amdgcn_mfma_f32_16x16x32_bf16(a, b, c, 0, 0, 0)

#define LR 72
#define OFF_VT 4608
#define OFF_Q  9216
#define ZROW   13824
#define LDS_TOT 13904    // 27,808 B -> 5 blocks/CU

// ws layout (ushort offsets): [0,49152) weight chunks; x2g (pi-packed bf16)
// at 65536. Needs ~33.7 MB of d_ws.
#define WS_X2 65536

// ---- weight prep (same mapping as R5..R19; 256-thread blocks, 4 chunks each) ----
__global__ void prep_weights(const float* __restrict__ wq, const float* __restrict__ wk,
                             const float* __restrict__ wv, const float* __restrict__ projw,
                             const float* __restrict__ fc1w, const float* __restrict__ fc2w,
                             unsigned short* __restrict__ ws) {
  int c = blockIdx.x * 4 + (threadIdx.x >> 6), l = threadIdx.x & 63;
  int g = l >> 4, jl = l & 15;
  int kind, T, ks;
  if (c < 8)       { kind = 0; T = c >> 1;        ks = c & 1; }
  else if (c < 16) { kind = 1; T = (c - 8) >> 1;  ks = (c - 8) & 1; }
  else if (c < 24) { kind = 2; T = (c - 16) >> 1; ks = (c - 16) & 1; }
  else if (c < 32) { kind = 3; T = (c - 24) >> 1; ks = (c - 24) & 1; }
  else if (c < 64) { kind = 4; T = (c - 32) >> 1; ks = (c - 32) & 1; }
  else             { kind = 5; T = (c - 64) >> 3; ks = (c - 64) & 7; }
  int n = 16 * T + jl;
  unsigned short* dst = ws + c * 512 + l * 8;
  #pragma unroll
  for (int jj = 0; jj < 8; ++jj) {
    int kp = 16 * (2 * (ks & 1) + (jj >> 2)) + 4 * g + (jj & 3);   // pi slot->col
    int kn = 32 * ks + 8 * g + jj;                                  // natural
    float v;
    if (kind == 0)      v = wq[(n >> 3) * 512 + kp * 8 + (n & 7)] * 0.18033688011f;
    else if (kind == 1) v = wk[(n >> 3) * 512 + kp * 8 + (n & 7)];
    else if (kind == 2) v = wv[(n >> 3) * 512 + kp * 8 + (n & 7)];
    else if (kind == 3) v = projw[kn * 64 + n];
    else if (kind == 4) v = fc1w[kp * 256 + n];
    else                v = fc2w[(64 * (ks >> 1) + kp) * 64 + n];
    dst[jj] = f2bf(v);
  }
}

// ========== K1: LN1 + QKV + attention + proj + residual ==========
// No weight staging: LDS 27.8 KB -> 5 blocks/CU (occupancy fills VALU pipe).
__global__ __launch_bounds__(256, 5) void block_attn(
    const float* __restrict__ x,
    const float* __restrict__ ln1w, const float* __restrict__ ln1b,
    const float* __restrict__ projb,
    unsigned short* __restrict__ wsm) {
  __shared__ __attribute__((aligned(16))) unsigned short lds[LDS_TOT];

  const int tid  = threadIdx.x;
  const int w    = tid >> 6;
  const int lane = tid & 63;
  const int g    = lane >> 4;
  const int jl   = lane & 15;
  const size_t b = blockIdx.x;
  const float* xb = x + b * 4096;
  const f32x4 zf = {0.f, 0.f, 0.f, 0.f};

  const int myrow = 16 * w + jl;
  const int krow  = myrow * LR;
  const int qrow  = OFF_Q + myrow * LR;
  const int sigb  = 32 * (w >> 1) + 8 * g + 4 * (w & 1);

  if (tid < 40) ((unsigned*)(lds + ZROW))[tid] = 0u;   // zero row (pre-barrier)

  // ---------- LN1 fully in registers; xw kept through proj ----------
  f32x4 xw[4];
  float mean, rstd;
  unsigned hr[8];
  {
    float s = 0.f, ss = 0.f;
    #pragma unroll
    for (int mi = 0; mi < 4; ++mi) {
      xw[mi] = *(const f32x4*)(xb + myrow * 64 + 16 * mi + 4 * g);
      #pragma unroll
      for (int r = 0; r < 4; ++r) { s += xw[mi][r]; ss += xw[mi][r] * xw[mi][r]; }
    }
    s  += __shfl_xor(s, 16, 64);  s  += __shfl_xor(s, 32, 64);
    ss += __shfl_xor(ss, 16, 64); ss += __shfl_xor(ss, 32, 64);
    mean = s * 0.015625f;
    rstd = rsqrtf(ss * 0.015625f - mean * mean + 1e-5f);
    #pragma unroll
    for (int mi = 0; mi < 4; ++mi) {
      f32x4 lw = *(const f32x4*)(ln1w + 16 * mi + 4 * g);
      f32x4 lb = *(const f32x4*)(ln1b + 16 * mi + 4 * g);
      float o0 = (xw[mi][0] - mean) * rstd * lw[0] + lb[0];
      float o1 = (xw[mi][1] - mean) * rstd * lw[1] + lb[1];
      float o2 = (xw[mi][2] - mean) * rstd * lw[2] + lb[2];
      float o3 = (xw[mi][3] - mean) * rstd * lw[3] + lb[3];
      hr[2 * mi] = pk2(o0, o1); hr[2 * mi + 1] = pk2(o2, o3);
    }
  }
  bf16x8 hb0 = frag((u32x4){hr[0], hr[1], hr[2], hr[3]});
  bf16x8 hb1 = frag((u32x4){hr[4], hr[5], hr[6], hr[7]});

  // ---------- QKV (rolled; weights from L2) ----------
  #pragma clang loop unroll(disable)
  for (int mt = 0; mt < 4; ++mt) {
    const unsigned short* wq8 = wsm + (2 * mt) * 512 + lane * 8;
    bf16x8 aq0 = *(const bf16x8*)(wq8);
    bf16x8 aq1 = *(const bf16x8*)(wq8 + 512);
    bf16x8 ak0 = *(const bf16x8*)(wq8 + 8 * 512);
    bf16x8 ak1 = *(const bf16x8*)(wq8 + 9 * 512);
    bf16x8 bv0 = *(const bf16x8*)(wq8 + 16 * 512);
    bf16x8 bv1 = *(const bf16x8*)(wq8 + 17 * 512);
    f32x4 q = MFMA16(aq0, hb0, zf); q = MFMA16(aq1, hb1, q);
    *(u32x2*)(lds + qrow + 16 * mt + 4 * g) = (u32x2){pk2(q[0], q[1]), pk2(q[2], q[3])};
    f32x4 kk = MFMA16(ak0, hb0, zf); kk = MFMA16(ak1, hb1, kk);
    *(u32x2*)(lds + krow + 16 * mt + 4 * g) = (u32x2){pk2(kk[0], kk[1]), pk2(kk[2], kk[3])};
    f32x4 vv = MFMA16(hb0, bv0, zf); vv = MFMA16(hb1, bv1, vv);
    *(u32x2*)(lds + OFF_VT + (16 * mt + jl) * LR + sigb) =
        (u32x2){pk2(vv[0], vv[1]), pk2(vv[2], vv[3])};
  }
  __syncthreads();   // barrier 1: publish Q, K, VT

  // ---------- attention: wave w owns heads {2w, 2w+1} ----------
  {
    const bool g0 = (g == 0), j8 = (jl < 8);
    const int ka0 = g0 ? ((0  + jl) * LR) : ZROW;
    const int ka1 = g0 ? ((16 + jl) * LR) : ZROW;
    const int ka2 = g0 ? ((32 + jl) * LR) : ZROW;
    const int ka3 = g0 ? ((48 + jl) * LR) : ZROW;
    const int qb0 = g0 ? (OFF_Q + (0  + jl) * LR) : ZROW;
    const int qb1 = g0 ? (OFF_Q + (16 + jl) * LR) : ZROW;
    const int qb2 = g0 ? (OFF_Q + (32 + jl) * LR) : ZROW;
    const int qb3 = g0 ? (OFF_Q + (48 + jl) * LR) : ZROW;
    const bool m0 = (4 * g + 0 <= jl), m1 = (4 * g + 1 <= jl);
    const bool m2 = (4 * g + 2 <= jl), m3 = (4 * g + 3 <= jl);
    #pragma clang loop unroll(disable)
    for (int hh = 0; hh < 2; ++hh) {
      const int ho = 16 * w + 8 * hh;
      const int vbase = j8 ? (OFF_VT + (ho + jl) * LR) : ZROW;
      bf16x8 bq0 = *(const bf16x8*)(lds + qb0 + ho);
      bf16x8 bq1 = *(const bf16x8*)(lds + qb1 + ho);
      bf16x8 bq2 = *(const bf16x8*)(lds + qb2 + ho);
      bf16x8 bq3 = *(const bf16x8*)(lds + qb3 + ho);
      bf16x8 k0  = *(const bf16x8*)(lds + ka0 + ho);
      bf16x8 k1  = *(const bf16x8*)(lds + ka1 + ho);
      bf16x8 k2  = *(const bf16x8*)(lds + ka2 + ho);
      bf16x8 k3  = *(const bf16x8*)(lds + ka3 + ho);
      bf16x8 aw0 = *(const bf16x8*)(lds + vbase + 8 * g);
      bf16x8 aw1 = *(const bf16x8*)(lds + vbase + 32 + 8 * g);
      wfence();
      f32x4 s00 = MFMA16(k0, bq0, zf);
      f32x4 s10 = MFMA16(k0, bq1, zf);
      f32x4 s11 = MFMA16(k1, bq1, zf);
      {   // qt 0
        float e0 = m0 ? EXP2(s00[0]) : 0.f, e1 = m1 ? EXP2(s00[1]) : 0.f;
        float e2 = m2 ? EXP2(s00[2]) : 0.f, e3 = m3 ? EXP2(s00[3]) : 0.f;
        float sum = (e0 + e1) + (e2 + e3);
        sum += __shfl_xor(sum, 16, 64); sum += __shfl_xor(sum, 32, 64);
        float inv = __builtin_amdgcn_rcpf(sum);
        bf16x8 bp0 = frag((u32x4){pk2(e0, e1), pk2(e2, e3), 0u, 0u});
        f32x4 pv = MFMA16(aw0, bp0, zf);
        if (g < 2)
          *(u32x2*)(lds + OFF_Q + jl * LR + ho + 4 * g) =
              (u32x2){pk2(pv[0] * inv, pv[1] * inv), pk2(pv[2] * inv, pv[3] * inv)};
      }
      {   // qt 1
        float a0 = EXP2(s10[0]), a1 = EXP2(s10[1]);
        float a2 = EXP2(s10[2]), a3 = EXP2(s10[3]);
        float e0 = m0 ? EXP2(s11[0]) : 0.f, e1 = m1 ? EXP2(s11[1]) : 0.f;
        float e2 = m2 ? EXP2(s11[2]) : 0.f, e3 = m3 ? EXP2(s11[3]) : 0.f;
        float sum = ((a0 + a1) + (a2 + a3)) + ((e0 + e1) + (e2 + e3));
        sum += __shfl_xor(sum, 16, 64); sum += __shfl_xor(sum, 32, 64);
        float inv = __builtin_amdgcn_rcpf(sum);
        bf16x8 bp0 = frag((u32x4){pk2(a0, a1), pk2(a2, a3), pk2(e0, e1), pk2(e2, e3)});
        f32x4 pv = MFMA16(aw0, bp0, zf);
        if (g < 2)
          *(u32x2*)(lds + OFF_Q + (16 + jl) * LR + ho + 4 * g) =
              (u32x2){pk2(pv[0] * inv, pv[1] * inv), pk2(pv[2] * inv, pv[3] * inv)};
      }
      f32x4 s20 = MFMA16(k0, bq2, zf);
      f32x4 s21 = MFMA16(k1, bq2, zf);
      f32x4 s22 = MFMA16(k2, bq2, zf);
      f32x4 s30 = MFMA16(k0, bq3, zf);
      f32x4 s31 = MFMA16(k1, bq3, zf);
      f32x4 s32 = MFMA16(k2, bq3, zf);
      f32x4 s33 = MFMA16(k3, bq3, zf);
      {   // qt 2
        float a0 = EXP2(s20[0]), a1 = EXP2(s20[1]);
        float a2 = EXP2(s20[2]), a3 = EXP2(s20[3]);
        float c0 = EXP2(s21[0]), c1 = EXP2(s21[1]);
        float c2 = EXP2(s21[2]), c3 = EXP2(s21[3]);
        float e0 = m0 ? EXP2(s22[0]) : 0.f, e1 = m1 ? EXP2(s22[1]) : 0.f;
        float e2 = m2 ? EXP2(s22[2]) : 0.f, e3 = m3 ? EXP2(s22[3]) : 0.f;
        float sum = ((a0 + a1) + (a2 + a3)) + ((c0 + c1) + (c2 + c3))
                  + ((e0 + e1) + (e2 + e3));
        sum += __shfl_xor(sum, 16, 64); sum += __shfl_xor(sum, 32, 64);
        float inv = __builtin_amdgcn_rcpf(sum);
        bf16x8 bp0 = frag((u32x4){pk2(a0, a1), pk2(a2, a3), pk2(c0, c1), pk2(c2, c3)});
        bf16x8 bp1 = frag((u32x4){pk2(e0, e1), pk2(e2, e3), 0u, 0u});
        f32x4 pv = MFMA16(aw0, bp0, zf); pv = MFMA16(aw1, bp1, pv);
        if (g < 2)
          *(u32x2*)(lds + OFF_Q + (32 + jl) * LR + ho + 4 * g) =
              (u32x2){pk2(pv[0] * inv, pv[1] * inv), pk2(pv[2] * inv, pv[3] * inv)};
      }
      {   // qt 3
        float a0 = EXP2(s30[0]), a1 = EXP2(s30[1]);
        float a2 = EXP2(s30[2]), a3 = EXP2(s30[3]);
        float c0 = EXP2(s31[0]), c1 = EXP2(s31[1]);
        float c2 = EXP2(s31[2]), c3 = EXP2(s31[3]);
        float d0 = EXP2(s32[0]), d1 = EXP2(s32[1]);
        float d2 = EXP2(s32[2]), d3 = EXP2(s32[3]);
        float e0 = m0 ? EXP2(s33[0]) : 0.f, e1 = m1 ? EXP2(s33[1]) : 0.f;
        float e2 = m2 ? EXP2(s33[2]) : 0.f, e3 = m3 ? EXP2(s33[3]) : 0.f;
        float sum = ((a0 + a1) + (a2 + a3)) + ((c0 + c1) + (c2 + c3))
                  + ((d0 + d1) + (d2 + d3)) + ((e0 + e1) + (e2 + e3));
        sum += __shfl_xor(sum, 16, 64); sum += __shfl_xor(sum, 32, 64);
        float inv = __builtin_amdgcn_rcpf(sum);
        bf16x8 bp0 = frag((u32x4){pk2(a0, a1), pk2(a2, a3), pk2(c0, c1), pk2(c2, c3)});
        bf16x8 bp1 = frag((u32x4){pk2(d0, d1), pk2(d2, d3), pk2(e0, e1), pk2(e2, e3)});
        f32x4 pv = MFMA16(aw0, bp0, zf); pv = MFMA16(aw1, bp1, pv);
        if (g < 2)
          *(u32x2*)(lds + OFF_Q + (48 + jl) * LR + ho + 4 * g) =
              (u32x2){pk2(pv[0] * inv, pv[1] * inv), pk2(pv[2] * inv, pv[3] * inv)};
      }
    }
  }
  __syncthreads();   // barrier 2: publish attn
  bf16x8 bat0 = *(const bf16x8*)(lds + qrow + 8 * g);
  bf16x8 bat1 = *(const bf16x8*)(lds + qrow + 32 + 8 * g);

  // ---------- proj + residual; store x2 pi-packed (ONLY output of K1) ----------
  {
    unsigned short* xrow = wsm + WS_X2 + (b * 64 + (size_t)myrow) * 64;
    f32x4 x20, x21, x22, x23;
    {
      bf16x8 a0 = *(const bf16x8*)(wsm + 24 * 512 + lane * 8);
      bf16x8 a1 = *(const bf16x8*)(wsm + 25 * 512 + lane * 8);
      f32x4 acc = MFMA16(a0, bat0, zf); acc = MFMA16(a1, bat1, acc);
      x20 = xw[0] + acc + *(const f32x4*)(projb + 4 * g);
    }
    {
      bf16x8 a0 = *(const bf16x8*)(wsm + 26 * 512 + lane * 8);
      bf16x8 a1 = *(const bf16x8*)(wsm + 27 * 512 + lane * 8);
      f32x4 acc = MFMA16(a0, bat0, zf); acc = MFMA16(a1, bat1, acc);
      x21 = xw[1] + acc + *(const f32x4*)(projb + 16 + 4 * g);
    }
    *(u32x4*)(xrow + 8 * g) = (u32x4){pk2(x20[0], x20[1]), pk2(x20[2], x20[3]),
                                      pk2(x21[0], x21[1]), pk2(x21[2], x21[3])};
    {
      bf16x8 a0 = *(const bf16x8*)(wsm + 28 * 512 + lane * 8);
      bf16x8 a1 = *(const bf16x8*)(wsm + 29 * 512 + lane * 8);
      f32x4 acc = MFMA16(a0, bat0, zf); acc = MFMA16(a1, bat1, acc);
      x22 = xw[2] + acc + *(const f32x4*)(projb + 32 + 4 * g);
    }
    {
      bf16x8 a0 = *(const bf16x8*)(wsm + 30 * 512 + lane * 8);
      bf16x8 a1 = *(const bf16x8*)(wsm + 31 * 512 + lane * 8);
      f32x4 acc = MFMA16(a0, bat0, zf); acc = MFMA16(a1, bat1, acc);
      x23 = xw[3] + acc + *(const f32x4*)(projb + 48 + 4 * g);
    }
    *(u32x4*)(xrow + 32 + 8 * g) = (u32x4){pk2(x22[0], x22[1]), pk2(x22[2], x22[3]),
                                           pk2(x23[0], x23[1]), pk2(x23[2], x23[3])};
  }
}

// ========== K2: LN2 + FF GEMM (R18-validated: 256 thr, LDS-staged, 8 passes) ==========
__global__ __launch_bounds__(256, 2) void ff_stream(
    const unsigned short* __restrict__ wsm,
    const float* __restrict__ ln2w, const float* __restrict__ ln2b,
    const float* __restrict__ fc1b, const float* __restrict__ fc2b,
    float* __restrict__ out) {
  __shared__ __attribute__((aligned(16))) unsigned short ldsw[32768];  // 64 KB

  const int tid  = threadIdx.x;
  const int w    = tid >> 6;
  const int lane = tid & 63;
  const int g    = lane >> 4;
  const int jl   = lane & 15;
  const int myrow = 16 * w + jl;
  const f32x4 zf = {0.f, 0.f, 0.f, 0.f};

  // stage fc1+fc2 chunks (orig 32..96 -> local 0..64): 64 KB coalesced
  {
    const u32x4* src = (const u32x4*)(wsm + 16384);
    u32x4* dst = (u32x4*)ldsw;
    #pragma unroll
    for (int k = 0; k < 16; ++k) dst[k * 256 + tid] = src[k * 256 + tid];
  }
  __syncthreads();

  // LN2 scales + fc2 bias (hoisted; L2-hot)
  f32x4 lw2[4], lb2[4], fb2[4];
  #pragma unroll
  for (int mi = 0; mi < 4; ++mi) {
    lw2[mi] = *(const f32x4*)(ln2w + 16 * mi + 4 * g);
    lb2[mi] = *(const f32x4*)(ln2b + 16 * mi + 4 * g);
    fb2[mi] = *(const f32x4*)(fc2b + 16 * mi + 4 * g);
  }

  const unsigned short* x2g = wsm + WS_X2;

  #pragma clang loop unroll(disable)
  for (int p = 0; p < 8; ++p) {
    const size_t t = (size_t)blockIdx.x * 512 + p * 64 + myrow;
    const unsigned short* xrow = x2g + t * 64;
    u32x4 v0 = *(const u32x4*)(xrow + 8 * g);
    u32x4 v1 = *(const u32x4*)(xrow + 32 + 8 * g);
    f32x4 x2[4];
    #pragma unroll
    for (int q = 0; q < 2; ++q) {
      u32x4 vv = q ? v1 : v0;
      x2[2 * q + 0][0] = bf2f((unsigned short)(vv[0] & 0xFFFF));
      x2[2 * q + 0][1] = bf2f((unsigned short)(vv[0] >> 16));
      x2[2 * q + 0][2] = bf2f((unsigned short)(vv[1] & 0xFFFF));
      x2[2 * q + 0][3] = bf2f((unsigned short)(vv[1] >> 16));
      x2[2 * q + 1][0] = bf2f((unsigned short)(vv[2] & 0xFFFF));
      x2[2 * q + 1][1] = bf2f((unsigned short)(vv[2] >> 16));
      x2[2 * q + 1][2] = bf2f((unsigned short)(vv[3] & 0xFFFF));
      x2[2 * q + 1][3] = bf2f((unsigned short)(vv[3] >> 16));
    }
    // LN2 in registers
    float s = 0.f, ss = 0.f;
    #pragma unroll
    for (int mi = 0; mi < 4; ++mi)
      #pragma unroll
      for (int r = 0; r < 4; ++r) { s += x2[mi][r]; ss += x2[mi][r] * x2[mi][r]; }
    s  += __shfl_xor(s, 16, 64);  s  += __shfl_xor(s, 32, 64);
    ss += __shfl_xor(ss, 16, 64); ss += __shfl_xor(ss, 32, 64);
    float mean2 = s * 0.015625f;
    float rstd2 = rsqrtf(ss * 0.015625f - mean2 * mean2 + 1e-5f);
    unsigned h2[8];
    #pragma unroll
    for (int mi = 0; mi < 4; ++mi) {
      float o0 = (x2[mi][0] - mean2) * rstd2 * lw2[mi][0] + lb2[mi][0];
      float o1 = (x2[mi][1] - mean2) * rstd2 * lw2[mi][1] + lb2[mi][1];
      float o2 = (x2[mi][2] - mean2) * rstd2 * lw2[mi][2] + lb2[mi][2];
      float o3 = (x2[mi][3] - mean2) * rstd2 * lw2[mi][3] + lb2[mi][3];
      h2[2 * mi] = pk2(o0, o1); h2[2 * mi + 1] = pk2(o2, o3);
    }
    bf16x8 hc0 = frag((u32x4){h2[0], h2[1], h2[2], h2[3]});
    bf16x8 hc1 = frag((u32x4){h2[4], h2[5], h2[6], h2[7]});

    f32x4 acc2[4];
    #pragma unroll
    for (int mi = 0; mi < 4; ++mi) acc2[mi] = zf;
    #pragma clang loop unroll(disable)
    for (int c = 0; c < 4; ++c) {
      const unsigned short* w1c = ldsw + (8 * c) * 512 + lane * 8;
      const unsigned short* w2c = ldsw + (32 + 2 * c) * 512 + lane * 8;
      const float* b1c = fc1b + 64 * c + 4 * g;
      unsigned fr0, fr1, fr2, fr3, fr4, fr5, fr6, fr7;
      {
        bf16x8 a0 = *(const bf16x8*)(w1c);
        bf16x8 a1 = *(const bf16x8*)(w1c + 512);
        f32x4 acc = MFMA16(a0, hc0, zf); acc = MFMA16(a1, hc1, acc);
        f32x4 bb = *(const f32x4*)(b1c);
        fr0 = pk2(fmaxf(acc[0] + bb[0], 0.f), fmaxf(acc[1] + bb[1], 0.f));
        fr1 = pk2(fmaxf(acc[2] + bb[2], 0.f), fmaxf(acc[3] + bb[3], 0.f));
      }
      {
        bf16x8 a0 = *(const bf16x8*)(w1c + 2 * 512);
        bf16x8 a1 = *(const bf16x8*)(w1c + 3 * 512);
        f32x4 acc = MFMA16(a0, hc0, zf); acc = MFMA16(a1, hc1, acc);
        f32x4 bb = *(const f32x4*)(b1c + 16);
        fr2 = pk2(fmaxf(acc[0] + bb[0], 0.f), fmaxf(acc[1] + bb[1], 0.f));
        fr3 = pk2(fmaxf(acc[2] + bb[2], 0.f), fmaxf(acc[3] + bb[3], 0.f));
      }
      {
        bf16x8 a0 = *(const bf16x8*)(w1c + 4 * 512);
        bf16x8 a1 = *(const bf16x8*)(w1c + 5 * 512);
        f32x4 acc = MFMA16(a0, hc0, zf); acc = MFMA16(a1, hc1, acc);
        f32x4 bb = *(const f32x4*)(b1c + 32);
        fr4 = pk2(fmaxf(acc[0] + bb[0], 0.f), fmaxf(acc[1] + bb[1], 0.f));
        fr5 = pk2(fmaxf(acc[2] + bb[2], 0.f), fmaxf(acc[3] + bb[3], 0.f));
      }
      {
        bf16x8 a0 = *(const bf16x8*)(w1c + 6 * 512);
        bf16x8 a1 = *(const bf16x8*)(w1c + 7 * 512);
        f32x4 acc = MFMA16(a0, hc0, zf); acc = MFMA16(a1, hc1, acc);
        f32x4 bb = *(const f32x4*)(b1c + 48);
        fr6 = pk2(fmaxf(acc[0] + bb[0], 0.f), fmaxf(acc[1] + bb[1], 0.f));
        fr7 = pk2(fmaxf(acc[2] + bb[2], 0.f), fmaxf(acc[3] + bb[3], 0.f));
      }
      bf16x8 bf0 = frag((u32x4){fr0, fr1, fr2, fr3});
      bf16x8 bf1 = frag((u32x4){fr4, fr5, fr6, fr7});
      #pragma unroll
      for (int mi = 0; mi < 4; ++mi) {
        bf16x8 w20 = *(const bf16x8*)(w2c + (8 * mi) * 512);
        bf16x8 w21 = *(const bf16x8*)(w2c + (8 * mi + 1) * 512);
        acc2[mi] = MFMA16(w20, bf0, acc2[mi]);
        acc2[mi] = MFMA16(w21, bf1, acc2[mi]);
      }
    }
    float* ob = out + t * 64;
    #pragma unroll
    for (int mi = 0; mi < 4; ++mi) {
      f32x4 o = x2[mi] + acc2[mi] + fb2[mi];
      *(f32x4*)(ob + 16 * mi + 4 * g) = o;
    }
  }
}

extern "C" void kernel_launch(void* const* d_in, const int* in_sizes, int n_in,
                              void* d_out, int out_size, void* d_ws, size_t ws_size,
                              hipStream_t stream) {
  const float* x     = (const float*)d_in[0];
  const float* ln1w  = (const float*)d_in[1];
  const float* ln1b  = (const float*)d_in[2];
  const float* wq    = (const float*)d_in[3];
  const float* wk    = (const float*)d_in[4];
  const float* wvp   = (const float*)d_in[5];
  const float* projw = (const float*)d_in[6];
  const float* projb = (const float*)d_in[7];
  const float* ln2w  = (const float*)d_in[8];
  const float* ln2b  = (const float*)d_in[9];
  const float* fc1w  = (const float*)d_in[10];
  const float* fc1b  = (const float*)d_in[11];
  const float* fc2w  = (const float*)d_in[12];
  const float* fc2b  = (const float*)d_in[13];
  unsigned short* ws = (unsigned short*)d_ws;   // needs ~33.7 MB
  float* out = (float*)d_out;

  prep_weights<<<dim3(24), dim3(256), 0, stream>>>(wq, wk, wvp, projw, fc1w, fc2w, ws);

  int nblk = in_sizes[0] / 4096;
  block_attn<<<dim3(nblk), dim3(256), 0, stream>>>(
      x, ln1w, ln1b, projb, ws);

  int nblk2 = (nblk * 64) / 512;   // 512 tokens per FF block
  ff_stream<<<dim3(nblk2), dim3(256), 0, stream>>>(ws, ln2w, ln2b, fc1b, fc2b, out);
}

// Round 21
// 82.087 us; speedup vs baseline: 1.0246x; 1.0223x over previous
//
#include <hip/hip_runtime.h>

typedef __attribute__((ext_vector_type(8))) short bf16x8;
typedef __attribute__((ext_vector_type(4))) float f32x4;
typedef __attribute__((ext_vector_type(2))) unsigned int u32x2;
typedef __attribute__((ext_vector_type(4))) unsigned int u32x4;

__device__ __forceinline__ unsigned short f2bf(float f) {
  return __builtin_bit_cast(unsigned short, (__bf16)f);
}
__device__ __forceinline__ unsigned pk2(float a, float b) {
  return (unsigned)f2bf(a) | ((unsigned)f2bf(b) << 16);
}
__device__ __forceinline__ float bf2f(unsigned short h) {
  unsigned u = ((unsigned)h) << 16;
  return __builtin_bit_cast(float, u);
}
__device__ __forceinline__ bf16x8 frag(u32x4 v) { return __builtin_bit_cast(bf16x8, v); }

#if __has_builtin(__builtin_amdgcn_exp2f)
#define EXP2(x) __builtin_amdgcn_exp2f(x)
#else
#define EXP2(x) exp2f(x)
#endif

__device__ __forceinline__ void wfence() {
  asm volatile("" ::: "memory");
  __builtin_amdgcn_wave_barrier();
}
__device__ __forceinline__ void sfence() { __builtin_amdgcn_sched_barrier(0); }

#define MFMA16(a, b, c) __builtin_amdgcn_mfma_f32_16x16x32_bf16(a, b, c, 0, 0, 0)

#define LR 72
#define OFF_VT 4608
#define OFF_Q  9216
#define ZROW   13824
#define OFF_WST 13904                 // staged QKV chunks 0..23 (12288 ushorts)
#define LDS_TOT (13904 + 12288)       // 52,384 B -> 3 blocks/CU

// ws layout (ushort offsets): [0,49152) weight chunks; x2g (pi-packed bf16)
// at 65536. Needs ~33.7 MB of d_ws.
#define WS_X2 65536

// ---- weight prep (same mapping as R5..R20; 256-thread blocks, 4 chunks each) ----
__global__ void prep_weights(const float* __restrict__ wq, const float* __restrict__ wk,
                             const float* __restrict__ wv, const float* __restrict__ projw,
                             const float* __restrict__ fc1w, const float* __restrict__ fc2w,
                             unsigned short* __restrict__ ws) {
  int c = blockIdx.x * 4 + (threadIdx.x >> 6), l = threadIdx.x & 63;
  int g = l >> 4, jl = l & 15;
  int kind, T, ks;
  if (c < 8)       { kind = 0; T = c >> 1;        ks = c & 1; }
  else if (c < 16) { kind = 1; T = (c - 8) >> 1;  ks = (c - 8) & 1; }
  else if (c < 24) { kind = 2; T = (c - 16) >> 1; ks = (c - 16) & 1; }
  else if (c < 32) { kind = 3; T = (c - 24) >> 1; ks = (c - 24) & 1; }
  else if (c < 64) { kind = 4; T = (c - 32) >> 1; ks = (c - 32) & 1; }
  else             { kind = 5; T = (c - 64) >> 3; ks = (c - 64) & 7; }
  int n = 16 * T + jl;
  unsigned short* dst = ws + c * 512 + l * 8;
  #pragma unroll
  for (int jj = 0; jj < 8; ++jj) {
    int kp = 16 * (2 * (ks & 1) + (jj >> 2)) + 4 * g + (jj & 3);   // pi slot->col
    int kn = 32 * ks + 8 * g + jj;                                  // natural
    float v;
    if (kind == 0)      v = wq[(n >> 3) * 512 + kp * 8 + (n & 7)] * 0.18033688011f;
    else if (kind == 1) v = wk[(n >> 3) * 512 + kp * 8 + (n & 7)];
    else if (kind == 2) v = wv[(n >> 3) * 512 + kp * 8 + (n & 7)];
    else if (kind == 3) v = projw[kn * 64 + n];
    else if (kind == 4) v = fc1w[kp * 256 + n];
    else                v = fc2w[(64 * (ks >> 1) + kp) * 64 + n];
    dst[jj] = f2bf(v);
  }
}

// ========== K1: LN1 + QKV + attention + proj + residual (R18-validated, 48.5us) ==========
__global__ __launch_bounds__(256, 3) void block_attn(
    const float* __restrict__ x,
    const float* __restrict__ ln1w, const float* __restrict__ ln1b,
    const float* __restrict__ projb,
    unsigned short* __restrict__ wsm) {
  __shared__ __attribute__((aligned(16))) unsigned short lds[LDS_TOT];

  const int tid  = threadIdx.x;
  const int w    = tid >> 6;
  const int lane = tid & 63;
  const int g    = lane >> 4;
  const int jl   = lane & 15;
  const size_t b = blockIdx.x;
  const float* xb = x + b * 4096;
  const f32x4 zf = {0.f, 0.f, 0.f, 0.f};

  const int myrow = 16 * w + jl;
  const int krow  = myrow * LR;
  const int qrow  = OFF_Q + myrow * LR;
  const int sigb  = 32 * (w >> 1) + 8 * g + 4 * (w & 1);

  // ---- stage-issue: QKV weight chunks 0..23 (24 KB) ----
  const u32x4* wsrc = (const u32x4*)wsm;
  u32x4 stg0 = wsrc[0 * 256 + tid], stg1 = wsrc[1 * 256 + tid];
  u32x4 stg2 = wsrc[2 * 256 + tid], stg3 = wsrc[3 * 256 + tid];
  u32x4 stg4 = wsrc[4 * 256 + tid], stg5 = wsrc[5 * 256 + tid];

  // ---------- LN1 fully in registers (covers stage-load latency) ----------
  f32x4 xw[4];
  float mean, rstd;
  unsigned hr[8];
  {
    float s = 0.f, ss = 0.f;
    #pragma unroll
    for (int mi = 0; mi < 4; ++mi) {
      xw[mi] = *(const f32x4*)(xb + myrow * 64 + 16 * mi + 4 * g);
      #pragma unroll
      for (int r = 0; r < 4; ++r) { s += xw[mi][r]; ss += xw[mi][r] * xw[mi][r]; }
    }
    s  += __shfl_xor(s, 16, 64);  s  += __shfl_xor(s, 32, 64);
    ss += __shfl_xor(ss, 16, 64); ss += __shfl_xor(ss, 32, 64);
    mean = s * 0.015625f;
    rstd = rsqrtf(ss * 0.015625f - mean * mean + 1e-5f);
    #pragma unroll
    for (int mi = 0; mi < 4; ++mi) {
      f32x4 lw = *(const f32x4*)(ln1w + 16 * mi + 4 * g);
      f32x4 lb = *(const f32x4*)(ln1b + 16 * mi + 4 * g);
      float o0 = (xw[mi][0] - mean) * rstd * lw[0] + lb[0];
      float o1 = (xw[mi][1] - mean) * rstd * lw[1] + lb[1];
      float o2 = (xw[mi][2] - mean) * rstd * lw[2] + lb[2];
      float o3 = (xw[mi][3] - mean) * rstd * lw[3] + lb[3];
      hr[2 * mi] = pk2(o0, o1); hr[2 * mi + 1] = pk2(o2, o3);
    }
  }
  bf16x8 hb0 = frag((u32x4){hr[0], hr[1], hr[2], hr[3]});
  bf16x8 hb1 = frag((u32x4){hr[4], hr[5], hr[6], hr[7]});

  // ---- stage-write + zero row, then publish ----
  {
    u32x4* wdst = (u32x4*)(lds + OFF_WST);
    wdst[0 * 256 + tid] = stg0; wdst[1 * 256 + tid] = stg1;
    wdst[2 * 256 + tid] = stg2; wdst[3 * 256 + tid] = stg3;
    wdst[4 * 256 + tid] = stg4; wdst[5 * 256 + tid] = stg5;
  }
  if (tid < 40) ((unsigned*)(lds + ZROW))[tid] = 0u;
  __syncthreads();   // barrier 0: staged weights + zero row visible

  // ---------- QKV (rolled; weights from LDS) ----------
  #pragma clang loop unroll(disable)
  for (int mt = 0; mt < 4; ++mt) {
    const unsigned short* wq8 = lds + OFF_WST + (2 * mt) * 512 + lane * 8;
    bf16x8 aq0 = *(const bf16x8*)(wq8);
    bf16x8 aq1 = *(const bf16x8*)(wq8 + 512);
    bf16x8 ak0 = *(const bf16x8*)(wq8 + 8 * 512);
    bf16x8 ak1 = *(const bf16x8*)(wq8 + 9 * 512);
    bf16x8 bv0 = *(const bf16x8*)(wq8 + 16 * 512);
    bf16x8 bv1 = *(const bf16x8*)(wq8 + 17 * 512);
    f32x4 q = MFMA16(aq0, hb0, zf); q = MFMA16(aq1, hb1, q);
    *(u32x2*)(lds + qrow + 16 * mt + 4 * g) = (u32x2){pk2(q[0], q[1]), pk2(q[2], q[3])};
    f32x4 kk = MFMA16(ak0, hb0, zf); kk = MFMA16(ak1, hb1, kk);
    *(u32x2*)(lds + krow + 16 * mt + 4 * g) = (u32x2){pk2(kk[0], kk[1]), pk2(kk[2], kk[3])};
    f32x4 vv = MFMA16(hb0, bv0, zf); vv = MFMA16(hb1, bv1, vv);
    *(u32x2*)(lds + OFF_VT + (16 * mt + jl) * LR + sigb) =
        (u32x2){pk2(vv[0], vv[1]), pk2(vv[2], vv[3])};
  }
  __syncthreads();   // barrier 1: publish Q, K, VT

  // ---------- attention: wave w owns heads {2w, 2w+1} ----------
  {
    const bool g0 = (g == 0), j8 = (jl < 8);
    const int ka0 = g0 ? ((0  + jl) * LR) : ZROW;
    const int ka1 = g0 ? ((16 + jl) * LR) : ZROW;
    const int ka2 = g0 ? ((32 + jl) * LR) : ZROW;
    const int ka3 = g0 ? ((48 + jl) * LR) : ZROW;
    const int qb0 = g0 ? (OFF_Q + (0  + jl) * LR) : ZROW;
    const int qb1 = g0 ? (OFF_Q + (16 + jl) * LR) : ZROW;
    const int qb2 = g0 ? (OFF_Q + (32 + jl) * LR) : ZROW;
    const int qb3 = g0 ? (OFF_Q + (48 + jl) * LR) : ZROW;
    const bool m0 = (4 * g + 0 <= jl), m1 = (4 * g + 1 <= jl);
    const bool m2 = (4 * g + 2 <= jl), m3 = (4 * g + 3 <= jl);
    #pragma clang loop unroll(disable)
    for (int hh = 0; hh < 2; ++hh) {
      const int ho = 16 * w + 8 * hh;
      const int vbase = j8 ? (OFF_VT + (ho + jl) * LR) : ZROW;
      bf16x8 bq0 = *(const bf16x8*)(lds + qb0 + ho);
      bf16x8 bq1 = *(const bf16x8*)(lds + qb1 + ho);
      bf16x8 bq2 = *(const bf16x8*)(lds + qb2 + ho);
      bf16x8 bq3 = *(const bf16x8*)(lds + qb3 + ho);
      bf16x8 k0  = *(const bf16x8*)(lds + ka0 + ho);
      bf16x8 k1  = *(const bf16x8*)(lds + ka1 + ho);
      bf16x8 k2  = *(const bf16x8*)(lds + ka2 + ho);
      bf16x8 k3  = *(const bf16x8*)(lds + ka3 + ho);
      bf16x8 aw0 = *(const bf16x8*)(lds + vbase + 8 * g);
      bf16x8 aw1 = *(const bf16x8*)(lds + vbase + 32 + 8 * g);
      wfence();
      f32x4 s00 = MFMA16(k0, bq0, zf);
      f32x4 s10 = MFMA16(k0, bq1, zf);
      f32x4 s11 = MFMA16(k1, bq1, zf);
      {   // qt 0
        float e0 = m0 ? EXP2(s00[0]) : 0.f, e1 = m1 ? EXP2(s00[1]) : 0.f;
        float e2 = m2 ? EXP2(s00[2]) : 0.f, e3 = m3 ? EXP2(s00[3]) : 0.f;
        float sum = (e0 + e1) + (e2 + e3);
        sum += __shfl_xor(sum, 16, 64); sum += __shfl_xor(sum, 32, 64);
        float inv = __builtin_amdgcn_rcpf(sum);
        bf16x8 bp0 = frag((u32x4){pk2(e0, e1), pk2(e2, e3), 0u, 0u});
        f32x4 pv = MFMA16(aw0, bp0, zf);
        if (g < 2)
          *(u32x2*)(lds + OFF_Q + jl * LR + ho + 4 * g) =
              (u32x2){pk2(pv[0] * inv, pv[1] * inv), pk2(pv[2] * inv, pv[3] * inv)};
      }
      {   // qt 1
        float a0 = EXP2(s10[0]), a1 = EXP2(s10[1]);
        float a2 = EXP2(s10[2]), a3 = EXP2(s10[3]);
        float e0 = m0 ? EXP2(s11[0]) : 0.f, e1 = m1 ? EXP2(s11[1]) : 0.f;
        float e2 = m2 ? EXP2(s11[2]) : 0.f, e3 = m3 ? EXP2(s11[3]) : 0.f;
        float sum = ((a0 + a1) + (a2 + a3)) + ((e0 + e1) + (e2 + e3));
        sum += __shfl_xor(sum, 16, 64); sum += __shfl_xor(sum, 32, 64);
        float inv = __builtin_amdgcn_rcpf(sum);
        bf16x8 bp0 = frag((u32x4){pk2(a0, a1), pk2(a2, a3), pk2(e0, e1), pk2(e2, e3)});
        f32x4 pv = MFMA16(aw0, bp0, zf);
        if (g < 2)
          *(u32x2*)(lds + OFF_Q + (16 + jl) * LR + ho + 4 * g) =
              (u32x2){pk2(pv[0] * inv, pv[1] * inv), pk2(pv[2] * inv, pv[3] * inv)};
      }
      f32x4 s20 = MFMA16(k0, bq2, zf);
      f32x4 s21 = MFMA16(k1, bq2, zf);
      f32x4 s22 = MFMA16(k2, bq2, zf);
      f32x4 s30 = MFMA16(k0, bq3, zf);
      f32x4 s31 = MFMA16(k1, bq3, zf);
      f32x4 s32 = MFMA16(k2, bq3, zf);
      f32x4 s33 = MFMA16(k3, bq3, zf);
      {   // qt 2
        float a0 = EXP2(s20[0]), a1 = EXP2(s20[1]);
        float a2 = EXP2(s20[2]), a3 = EXP2(s20[3]);
        float c0 = EXP2(s21[0]), c1 = EXP2(s21[1]);
        float c2 = EXP2(s21[2]), c3 = EXP2(s21[3]);
        float e0 = m0 ? EXP2(s22[0]) : 0.f, e1 = m1 ? EXP2(s22[1]) : 0.f;
        float e2 = m2 ? EXP2(s22[2]) : 0.f, e3 = m3 ? EXP2(s22[3]) : 0.f;
        float sum = ((a0 + a1) + (a2 + a3)) + ((c0 + c1) + (c2 + c3))
                  + ((e0 + e1) + (e2 + e3));
        sum += __shfl_xor(sum, 16, 64); sum += __shfl_xor(sum, 32, 64);
        float inv = __builtin_amdgcn_rcpf(sum);
        bf16x8 bp0 = frag((u32x4){pk2(a0, a1), pk2(a2, a3), pk2(c0, c1), pk2(c2, c3)});
        bf16x8 bp1 = frag((u32x4){pk2(e0, e1), pk2(e2, e3), 0u, 0u});
        f32x4 pv = MFMA16(aw0, bp0, zf); pv = MFMA16(aw1, bp1, pv);
        if (g < 2)
          *(u32x2*)(lds + OFF_Q + (32 + jl) * LR + ho + 4 * g) =
              (u32x2){pk2(pv[0] * inv, pv[1] * inv), pk2(pv[2] * inv, pv[3] * inv)};
      }
      {   // qt 3
        float a0 = EXP2(s30[0]), a1 = EXP2(s30[1]);
        float a2 = EXP2(s30[2]), a3 = EXP2(s30[3]);
        float c0 = EXP2(s31[0]), c1 = EXP2(s31[1]);
        float c2 = EXP2(s31[2]), c3 = EXP2(s31[3]);
        float d0 = EXP2(s32[0]), d1 = EXP2(s32[1]);
        float d2 = EXP2(s32[2]), d3 = EXP2(s32[3]);
        float e0 = m0 ? EXP2(s33[0]) : 0.f, e1 = m1 ? EXP2(s33[1]) : 0.f;
        float e2 = m2 ? EXP2(s33[2]) : 0.f, e3 = m3 ? EXP2(s33[3]) : 0.f;
        float sum = ((a0 + a1) + (a2 + a3)) + ((c0 + c1) + (c2 + c3))
                  + ((d0 + d1) + (d2 + d3)) + ((e0 + e1) + (e2 + e3));
        sum += __shfl_xor(sum, 16, 64); sum += __shfl_xor(sum, 32, 64);
        float inv = __builtin_amdgcn_rcpf(sum);
        bf16x8 bp0 = frag((u32x4){pk2(a0, a1), pk2(a2, a3), pk2(c0, c1), pk2(c2, c3)});
        bf16x8 bp1 = frag((u32x4){pk2(d0, d1), pk2(d2, d3), pk2(e0, e1), pk2(e2, e3)});
        f32x4 pv = MFMA16(aw0, bp0, zf); pv = MFMA16(aw1, bp1, pv);
        if (g < 2)
          *(u32x2*)(lds + OFF_Q + (48 + jl) * LR + ho + 4 * g) =
              (u32x2){pk2(pv[0] * inv, pv[1] * inv), pk2(pv[2] * inv, pv[3] * inv)};
      }
    }
  }
  __syncthreads();   // barrier 2: publish attn
  bf16x8 bat0 = *(const bf16x8*)(lds + qrow + 8 * g);
  bf16x8 bat1 = *(const bf16x8*)(lds + qrow + 32 + 8 * g);

  // ---------- proj + residual; store x2 pi-packed (ONLY output of K1) ----------
  {
    unsigned short* xrow = wsm + WS_X2 + (b * 64 + (size_t)myrow) * 64;
    f32x4 x20, x21, x22, x23;
    {
      bf16x8 a0 = *(const bf16x8*)(wsm + 24 * 512 + lane * 8);
      bf16x8 a1 = *(const bf16x8*)(wsm + 25 * 512 + lane * 8);
      f32x4 acc = MFMA16(a0, bat0, zf); acc = MFMA16(a1, bat1, acc);
      x20 = xw[0] + acc + *(const f32x4*)(projb + 4 * g);
    }
    {
      bf16x8 a0 = *(const bf16x8*)(wsm + 26 * 512 + lane * 8);
      bf16x8 a1 = *(const bf16x8*)(wsm + 27 * 512 + lane * 8);
      f32x4 acc = MFMA16(a0, bat0, zf); acc = MFMA16(a1, bat1, acc);
      x21 = xw[1] + acc + *(const f32x4*)(projb + 16 + 4 * g);
    }
    *(u32x4*)(xrow + 8 * g) = (u32x4){pk2(x20[0], x20[1]), pk2(x20[2], x20[3]),
                                      pk2(x21[0], x21[1]), pk2(x21[2], x21[3])};
    {
      bf16x8 a0 = *(const bf16x8*)(wsm + 28 * 512 + lane * 8);
      bf16x8 a1 = *(const bf16x8*)(wsm + 29 * 512 + lane * 8);
      f32x4 acc = MFMA16(a0, bat0, zf); acc = MFMA16(a1, bat1, acc);
      x22 = xw[2] + acc + *(const f32x4*)(projb + 32 + 4 * g);
    }
    {
      bf16x8 a0 = *(const bf16x8*)(wsm + 30 * 512 + lane * 8);
      bf16x8 a1 = *(const bf16x8*)(wsm + 31 * 512 + lane * 8);
      f32x4 acc = MFMA16(a0, bat0, zf); acc = MFMA16(a1, bat1, acc);
      x23 = xw[3] + acc + *(const f32x4*)(projb + 48 + 4 * g);
    }
    *(u32x4*)(xrow + 32 + 8 * g) = (u32x4){pk2(x22[0], x22[1]), pk2(x22[2], x22[3]),
                                           pk2(x23[0], x23[1]), pk2(x23[2], x23[3])};
  }
}

// ========== K2: LN2 + FF GEMM (LDS-staged, 8 passes, pipelined x2 loads) ==========
__global__ __launch_bounds__(256, 2) void ff_stream(
    const unsigned short* __restrict__ wsm,
    const float* __restrict__ ln2w, const float* __restrict__ ln2b,
    const float* __restrict__ fc1b, const float* __restrict__ fc2b,
    float* __restrict__ out) {
  __shared__ __attribute__((aligned(16))) unsigned short ldsw[32768];  // 64 KB

  const int tid  = threadIdx.x;
  const int w    = tid >> 6;
  const int lane = tid & 63;
  const int g    = lane >> 4;
  const int jl   = lane & 15;
  const int myrow = 16 * w + jl;
  const f32x4 zf = {0.f, 0.f, 0.f, 0.f};

  // stage fc1+fc2 chunks (orig 32..96 -> local 0..64): 64 KB coalesced
  {
    const u32x4* src = (const u32x4*)(wsm + 16384);
    u32x4* dst = (u32x4*)ldsw;
    #pragma unroll
    for (int k = 0; k < 16; ++k) dst[k * 256 + tid] = src[k * 256 + tid];
  }
  __syncthreads();

  // LN2 scales + fc2 bias (hoisted; L2-hot)
  f32x4 lw2[4], lb2[4], fb2[4];
  #pragma unroll
  for (int mi = 0; mi < 4; ++mi) {
    lw2[mi] = *(const f32x4*)(ln2w + 16 * mi + 4 * g);
    lb2[mi] = *(const f32x4*)(ln2b + 16 * mi + 4 * g);
    fb2[mi] = *(const f32x4*)(fc2b + 16 * mi + 4 * g);
  }

  const unsigned short* x2g = wsm + WS_X2;
  const size_t tbase = (size_t)blockIdx.x * 512 + myrow;

  // prologue: preload pass-0 x2 row (loop-carried registers)
  u32x4 v0 = *(const u32x4*)(x2g + tbase * 64 + 8 * g);
  u32x4 v1 = *(const u32x4*)(x2g + tbase * 64 + 32 + 8 * g);

  #pragma clang loop unroll(disable)
  for (int p = 0; p < 8; ++p) {
    const size_t t = tbase + p * 64;
    f32x4 x2[4];
    #pragma unroll
    for (int q = 0; q < 2; ++q) {
      u32x4 vv = q ? v1 : v0;
      x2[2 * q + 0][0] = bf2f((unsigned short)(vv[0] & 0xFFFF));
      x2[2 * q + 0][1] = bf2f((unsigned short)(vv[0] >> 16));
      x2[2 * q + 0][2] = bf2f((unsigned short)(vv[1] & 0xFFFF));
      x2[2 * q + 0][3] = bf2f((unsigned short)(vv[1] >> 16));
      x2[2 * q + 1][0] = bf2f((unsigned short)(vv[2] & 0xFFFF));
      x2[2 * q + 1][1] = bf2f((unsigned short)(vv[2] >> 16));
      x2[2 * q + 1][2] = bf2f((unsigned short)(vv[3] & 0xFFFF));
      x2[2 * q + 1][3] = bf2f((unsigned short)(vv[3] >> 16));
    }
    // T14 split: issue NEXT pass's x2 loads now; latency hides under LN2+FF.
    if (p < 7) {
      v0 = *(const u32x4*)(x2g + (t + 64) * 64 + 8 * g);
      v1 = *(const u32x4*)(x2g + (t + 64) * 64 + 32 + 8 * g);
    }
    sfence();   // keep the prefetch issue ahead of the compute body

    // LN2 in registers
    float s = 0.f, ss = 0.f;
    #pragma unroll
    for (int mi = 0; mi < 4; ++mi)
      #pragma unroll
      for (int r = 0; r < 4; ++r) { s += x2[mi][r]; ss += x2[mi][r] * x2[mi][r]; }
    s  += __shfl_xor(s, 16, 64);  s  += __shfl_xor(s, 32, 64);
    ss += __shfl_xor(ss, 16, 64); ss += __shfl_xor(ss, 32, 64);
    float mean2 = s * 0.015625f;
    float rstd2 = rsqrtf(ss * 0.015625f - mean2 * mean2 + 1e-5f);
    unsigned h2[8];
    #pragma unroll
    for (int mi = 0; mi < 4; ++mi) {
      float o0 = (x2[mi][0] - mean2) * rstd2 * lw2[mi][0] + lb2[mi][0];
      float o1 = (x2[mi][1] - mean2) * rstd2 * lw2[mi][1] + lb2[mi][1];
      float o2 = (x2[mi][2] - mean2) * rstd2 * lw2[mi][2] + lb2[mi][2];
      float o3 = (x2[mi][3] - mean2) * rstd2 * lw2[mi][3] + lb2[mi][3];
      h2[2 * mi] = pk2(o0, o1); h2[2 * mi + 1] = pk2(o2, o3);
    }
    bf16x8 hc0 = frag((u32x4){h2[0], h2[1], h2[2], h2[3]});
    bf16x8 hc1 = frag((u32x4){h2[4], h2[5], h2[6], h2[7]});

    f32x4 acc2[4];
    #pragma unroll
    for (int mi = 0; mi < 4; ++mi) acc2[mi] = zf;
    #pragma clang loop unroll(disable)
    for (int c = 0; c < 4; ++c) {
      const unsigned short* w1c = ldsw + (8 * c) * 512 + lane * 8;
      const unsigned short* w2c = ldsw + (32 + 2 * c) * 512 + lane * 8;
      const float* b1c = fc1b + 64 * c + 4 * g;
      unsigned fr0, fr1, fr2, fr3, fr4, fr5, fr6, fr7;
      {
        bf16x8 a0 = *(const bf16x8*)(w1c);
        bf16x8 a1 = *(const bf16x8*)(w1c + 512);
        f32x4 acc = MFMA16(a0, hc0, zf); acc = MFMA16(a1, hc1, acc);
        f32x4 bb = *(const f32x4*)(b1c);
        fr0 = pk2(fmaxf(acc[0] + bb[0], 0.f), fmaxf(acc[1] + bb[1], 0.f));
        fr1 = pk2(fmaxf(acc[2] + bb[2], 0.f), fmaxf(acc[3] + bb[3], 0.f));
      }
      {
        bf16x8 a0 = *(const bf16x8*)(w1c + 2 * 512);
        bf16x8 a1 = *(const bf16x8*)(w1c + 3 * 512);
        f32x4 acc = MFMA16(a0, hc0, zf); acc = MFMA16(a1, hc1, acc);
        f32x4 bb = *(const f32x4*)(b1c + 16);
        fr2 = pk2(fmaxf(acc[0] + bb[0], 0.f), fmaxf(acc[1] + bb[1], 0.f));
        fr3 = pk2(fmaxf(acc[2] + bb[2], 0.f), fmaxf(acc[3] + bb[3], 0.f));
      }
      {
        bf16x8 a0 = *(const bf16x8*)(w1c + 4 * 512);
        bf16x8 a1 = *(const bf16x8*)(w1c + 5 * 512);
        f32x4 acc = MFMA16(a0, hc0, zf); acc = MFMA16(a1, hc1, acc);
        f32x4 bb = *(const f32x4*)(b1c + 32);
        fr4 = pk2(fmaxf(acc[0] + bb[0], 0.f), fmaxf(acc[1] + bb[1], 0.f));
        fr5 = pk2(fmaxf(acc[2] + bb[2], 0.f), fmaxf(acc[3] + bb[3], 0.f));
      }
      {
        bf16x8 a0 = *(const bf16x8*)(w1c + 6 * 512);
        bf16x8 a1 = *(const bf16x8*)(w1c + 7 * 512);
        f32x4 acc = MFMA16(a0, hc0, zf); acc = MFMA16(a1, hc1, acc);
        f32x4 bb = *(const f32x4*)(b1c + 48);
        fr6 = pk2(fmaxf(acc[0] + bb[0], 0.f), fmaxf(acc[1] + bb[1], 0.f));
        fr7 = pk2(fmaxf(acc[2] + bb[2], 0.f), fmaxf(acc[3] + bb[3], 0.f));
      }
      bf16x8 bf0 = frag((u32x4){fr0, fr1, fr2, fr3});
      bf16x8 bf1 = frag((u32x4){fr4, fr5, fr6, fr7});
      #pragma unroll
      for (int mi = 0; mi < 4; ++mi) {
        bf16x8 w20 = *(const bf16x8*)(w2c + (8 * mi) * 512);
        bf16x8 w21 = *(const bf16x8*)(w2c + (8 * mi + 1) * 512);
        acc2[mi] = MFMA16(w20, bf0, acc2[mi]);
        acc2[mi] = MFMA16(w21, bf1, acc2[mi]);
      }
    }
    float* ob = out + t * 64;
    #pragma unroll
    for (int mi = 0; mi < 4; ++mi) {
      f32x4 o = x2[mi] + acc2[mi] + fb2[mi];
      *(f32x4*)(ob + 16 * mi + 4 * g) = o;
    }
  }
}

extern "C" void kernel_launch(void* const* d_in, const int* in_sizes, int n_in,
                              void* d_out, int out_size, void* d_ws, size_t ws_size,
                              hipStream_t stream) {
  const float* x     = (const float*)d_in[0];
  const float* ln1w  = (const float*)d_in[1];
  const float* ln1b  = (const float*)d_in[2];
  const float* wq    = (const float*)d_in[3];
  const float* wk    = (const float*)d_in[4];
  const float* wvp   = (const float*)d_in[5];
  const float* projw = (const float*)d_in[6];
  const float* projb = (const float*)d_in[7];
  const float* ln2w  = (const float*)d_in[8];
  const float* ln2b  = (const float*)d_in[9];
  const float* fc1w  = (const float*)d_in[10];
  const float* fc1b  = (const float*)d_in[11];
  const float* fc2w  = (const float*)d_in[12];
  const float* fc2b  = (const float*)d_in[13];
  unsigned short* ws = (unsigned short*)d_ws;   // needs ~33.7 MB
  float* out = (float*)d_out;

  prep_weights<<<dim3(24), dim3(256), 0, stream>>>(wq, wk, wvp, projw, fc1w, fc2w, ws);

  int nblk = in_sizes[0] / 4096;
  block_attn<<<dim3(nblk), dim3(256), 0, stream>>>(
      x, ln1w, ln1b, projb, ws);

  int nblk2 = (nblk * 64) / 512;   // 512 tokens per FF block
  ff_stream<<<dim3(nblk2), dim3(256), 0, stream>>>(ws, ln2w, ln2b, fc1b, fc2b, out);
}

// Round 22
// 79.869 us; speedup vs baseline: 1.0531x; 1.0278x over previous
//
#include <hip/hip_runtime.h>

typedef __attribute__((ext_vector_type(8))) short bf16x8;
typedef __attribute__((ext_vector_type(4))) float f32x4;
typedef __attribute__((ext_vector_type(2))) unsigned int u32x2;
typedef __attribute__((ext_vector_type(4))) unsigned int u32x4;

__device__ __forceinline__ unsigned short f2bf(float f) {
  return __builtin_bit_cast(unsigned short, (__bf16)f);
}
__device__ __forceinline__ unsigned pk2(float a, float b) {
  return (unsigned)f2bf(a) | ((unsigned)f2bf(b) << 16);
}
__device__ __forceinline__ float bf2f(unsigned short h) {
  unsigned u = ((unsigned)h) << 16;
  return __builtin_bit_cast(float, u);
}
__device__ __forceinline__ bf16x8 frag(u32x4 v) { return __builtin_bit_cast(bf16x8, v); }

#if __has_builtin(__builtin_amdgcn_exp2f)
#define EXP2(x) __builtin_amdgcn_exp2f(x)
#else
#define EXP2(x) exp2f(x)
#endif

__device__ __forceinline__ void wfence() {
  asm volatile("" ::: "memory");
  __builtin_amdgcn_wave_barrier();
}
__device__ __forceinline__ void sfence() { __builtin_amdgcn_sched_barrier(0); }

#define MFMA16(a, b, c) __builtin_amdgcn_mfma_f32_16x16x32_bf16(a, b, c, 0, 0, 0)

#define LR 72
#define OFF_VT 4608
#define OFF_Q  9216
#define ZROW   13824
#define OFF_WST 13904                 // staged QKV chunks 0..23 (12288 ushorts)
#define LDS_TOT (13904 + 12288)       // 52,384 B -> 3 blocks/CU

// ws layout (ushort offsets): [0,49152) weight chunks; x2g (pi-packed bf16)
// at 65536. Needs ~33.7 MB of d_ws.
#define WS_X2 65536

// ---- weight prep (same mapping as R5..R21; 256-thread blocks, 4 chunks each) ----
__global__ void prep_weights(const float* __restrict__ wq, const float* __restrict__ wk,
                             const float* __restrict__ wv, const float* __restrict__ projw,
                             const float* __restrict__ fc1w, const float* __restrict__ fc2w,
                             unsigned short* __restrict__ ws) {
  int c = blockIdx.x * 4 + (threadIdx.x >> 6), l = threadIdx.x & 63;
  int g = l >> 4, jl = l & 15;
  int kind, T, ks;
  if (c < 8)       { kind = 0; T = c >> 1;        ks = c & 1; }
  else if (c < 16) { kind = 1; T = (c - 8) >> 1;  ks = (c - 8) & 1; }
  else if (c < 24) { kind = 2; T = (c - 16) >> 1; ks = (c - 16) & 1; }
  else if (c < 32) { kind = 3; T = (c - 24) >> 1; ks = (c - 24) & 1; }
  else if (c < 64) { kind = 4; T = (c - 32) >> 1; ks = (c - 32) & 1; }
  else             { kind = 5; T = (c - 64) >> 3; ks = (c - 64) & 7; }
  int n = 16 * T + jl;
  unsigned short* dst = ws + c * 512 + l * 8;
  #pragma unroll
  for (int jj = 0; jj < 8; ++jj) {
    int kp = 16 * (2 * (ks & 1) + (jj >> 2)) + 4 * g + (jj & 3);   // pi slot->col
    int kn = 32 * ks + 8 * g + jj;                                  // natural
    float v;
    if (kind == 0)      v = wq[(n >> 3) * 512 + kp * 8 + (n & 7)] * 0.18033688011f;
    else if (kind == 1) v = wk[(n >> 3) * 512 + kp * 8 + (n & 7)];
    else if (kind == 2) v = wv[(n >> 3) * 512 + kp * 8 + (n & 7)];
    else if (kind == 3) v = projw[kn * 64 + n];
    else if (kind == 4) v = fc1w[kp * 256 + n];
    else                v = fc2w[(64 * (ks >> 1) + kp) * 64 + n];
    dst[jj] = f2bf(v);
  }
}

// ========== K1: LN1 + QKV + attention + proj + residual (R18/R21-validated) ==========
__global__ __launch_bounds__(256, 3) void block_attn(
    const float* __restrict__ x,
    const float* __restrict__ ln1w, const float* __restrict__ ln1b,
    const float* __restrict__ projb,
    unsigned short* __restrict__ wsm) {
  __shared__ __attribute__((aligned(16))) unsigned short lds[LDS_TOT];

  const int tid  = threadIdx.x;
  const int w    = tid >> 6;
  const int lane = tid & 63;
  const int g    = lane >> 4;
  const int jl   = lane & 15;
  const size_t b = blockIdx.x;
  const float* xb = x + b * 4096;
  const f32x4 zf = {0.f, 0.f, 0.f, 0.f};

  const int myrow = 16 * w + jl;
  const int krow  = myrow * LR;
  const int qrow  = OFF_Q + myrow * LR;
  const int sigb  = 32 * (w >> 1) + 8 * g + 4 * (w & 1);

  // ---- stage-issue: QKV weight chunks 0..23 (24 KB) ----
  const u32x4* wsrc = (const u32x4*)wsm;
  u32x4 stg0 = wsrc[0 * 256 + tid], stg1 = wsrc[1 * 256 + tid];
  u32x4 stg2 = wsrc[2 * 256 + tid], stg3 = wsrc[3 * 256 + tid];
  u32x4 stg4 = wsrc[4 * 256 + tid], stg5 = wsrc[5 * 256 + tid];

  // ---------- LN1 fully in registers (covers stage-load latency) ----------
  f32x4 xw[4];
  float mean, rstd;
  unsigned hr[8];
  {
    float s = 0.f, ss = 0.f;
    #pragma unroll
    for (int mi = 0; mi < 4; ++mi) {
      xw[mi] = *(const f32x4*)(xb + myrow * 64 + 16 * mi + 4 * g);
      #pragma unroll
      for (int r = 0; r < 4; ++r) { s += xw[mi][r]; ss += xw[mi][r] * xw[mi][r]; }
    }
    s  += __shfl_xor(s, 16, 64);  s  += __shfl_xor(s, 32, 64);
    ss += __shfl_xor(ss, 16, 64); ss += __shfl_xor(ss, 32, 64);
    mean = s * 0.015625f;
    rstd = rsqrtf(ss * 0.015625f - mean * mean + 1e-5f);
    #pragma unroll
    for (int mi = 0; mi < 4; ++mi) {
      f32x4 lw = *(const f32x4*)(ln1w + 16 * mi + 4 * g);
      f32x4 lb = *(const f32x4*)(ln1b + 16 * mi + 4 * g);
      float o0 = (xw[mi][0] - mean) * rstd * lw[0] + lb[0];
      float o1 = (xw[mi][1] - mean) * rstd * lw[1] + lb[1];
      float o2 = (xw[mi][2] - mean) * rstd * lw[2] + lb[2];
      float o3 = (xw[mi][3] - mean) * rstd * lw[3] + lb[3];
      hr[2 * mi] = pk2(o0, o1); hr[2 * mi + 1] = pk2(o2, o3);
    }
  }
  bf16x8 hb0 = frag((u32x4){hr[0], hr[1], hr[2], hr[3]});
  bf16x8 hb1 = frag((u32x4){hr[4], hr[5], hr[6], hr[7]});

  // ---- stage-write + zero row, then publish ----
  {
    u32x4* wdst = (u32x4*)(lds + OFF_WST);
    wdst[0 * 256 + tid] = stg0; wdst[1 * 256 + tid] = stg1;
    wdst[2 * 256 + tid] = stg2; wdst[3 * 256 + tid] = stg3;
    wdst[4 * 256 + tid] = stg4; wdst[5 * 256 + tid] = stg5;
  }
  if (tid < 40) ((unsigned*)(lds + ZROW))[tid] = 0u;
  __syncthreads();   // barrier 0: staged weights + zero row visible

  // ---------- QKV (rolled; weights from LDS) ----------
  #pragma clang loop unroll(disable)
  for (int mt = 0; mt < 4; ++mt) {
    const unsigned short* wq8 = lds + OFF_WST + (2 * mt) * 512 + lane * 8;
    bf16x8 aq0 = *(const bf16x8*)(wq8);
    bf16x8 aq1 = *(const bf16x8*)(wq8 + 512);
    bf16x8 ak0 = *(const bf16x8*)(wq8 + 8 * 512);
    bf16x8 ak1 = *(const bf16x8*)(wq8 + 9 * 512);
    bf16x8 bv0 = *(const bf16x8*)(wq8 + 16 * 512);
    bf16x8 bv1 = *(const bf16x8*)(wq8 + 17 * 512);
    f32x4 q = MFMA16(aq0, hb0, zf); q = MFMA16(aq1, hb1, q);
    *(u32x2*)(lds + qrow + 16 * mt + 4 * g) = (u32x2){pk2(q[0], q[1]), pk2(q[2], q[3])};
    f32x4 kk = MFMA16(ak0, hb0, zf); kk = MFMA16(ak1, hb1, kk);
    *(u32x2*)(lds + krow + 16 * mt + 4 * g) = (u32x2){pk2(kk[0], kk[1]), pk2(kk[2], kk[3])};
    f32x4 vv = MFMA16(hb0, bv0, zf); vv = MFMA16(hb1, bv1, vv);
    *(u32x2*)(lds + OFF_VT + (16 * mt + jl) * LR + sigb) =
        (u32x2){pk2(vv[0], vv[1]), pk2(vv[2], vv[3])};
  }
  __syncthreads();   // barrier 1: publish Q, K, VT

  // ---------- attention: wave w owns heads {2w, 2w+1} ----------
  {
    const bool g0 = (g == 0), j8 = (jl < 8);
    const int ka0 = g0 ? ((0  + jl) * LR) : ZROW;
    const int ka1 = g0 ? ((16 + jl) * LR) : ZROW;
    const int ka2 = g0 ? ((32 + jl) * LR) : ZROW;
    const int ka3 = g0 ? ((48 + jl) * LR) : ZROW;
    const int qb0 = g0 ? (OFF_Q + (0  + jl) * LR) : ZROW;
    const int qb1 = g0 ? (OFF_Q + (16 + jl) * LR) : ZROW;
    const int qb2 = g0 ? (OFF_Q + (32 + jl) * LR) : ZROW;
    const int qb3 = g0 ? (OFF_Q + (48 + jl) * LR) : ZROW;
    const bool m0 = (4 * g + 0 <= jl), m1 = (4 * g + 1 <= jl);
    const bool m2 = (4 * g + 2 <= jl), m3 = (4 * g + 3 <= jl);
    #pragma clang loop unroll(disable)
    for (int hh = 0; hh < 2; ++hh) {
      const int ho = 16 * w + 8 * hh;
      const int vbase = j8 ? (OFF_VT + (ho + jl) * LR) : ZROW;
      bf16x8 bq0 = *(const bf16x8*)(lds + qb0 + ho);
      bf16x8 bq1 = *(const bf16x8*)(lds + qb1 + ho);
      bf16x8 bq2 = *(const bf16x8*)(lds + qb2 + ho);
      bf16x8 bq3 = *(const bf16x8*)(lds + qb3 + ho);
      bf16x8 k0  = *(const bf16x8*)(lds + ka0 + ho);
      bf16x8 k1  = *(const bf16x8*)(lds + ka1 + ho);
      bf16x8 k2  = *(const bf16x8*)(lds + ka2 + ho);
      bf16x8 k3  = *(const bf16x8*)(lds + ka3 + ho);
      bf16x8 aw0 = *(const bf16x8*)(lds + vbase + 8 * g);
      bf16x8 aw1 = *(const bf16x8*)(lds + vbase + 32 + 8 * g);
      wfence();
      f32x4 s00 = MFMA16(k0, bq0, zf);
      f32x4 s10 = MFMA16(k0, bq1, zf);
      f32x4 s11 = MFMA16(k1, bq1, zf);
      {   // qt 0
        float e0 = m0 ? EXP2(s00[0]) : 0.f, e1 = m1 ? EXP2(s00[1]) : 0.f;
        float e2 = m2 ? EXP2(s00[2]) : 0.f, e3 = m3 ? EXP2(s00[3]) : 0.f;
        float sum = (e0 + e1) + (e2 + e3);
        sum += __shfl_xor(sum, 16, 64); sum += __shfl_xor(sum, 32, 64);
        float inv = __builtin_amdgcn_rcpf(sum);
        bf16x8 bp0 = frag((u32x4){pk2(e0, e1), pk2(e2, e3), 0u, 0u});
        f32x4 pv = MFMA16(aw0, bp0, zf);
        if (g < 2)
          *(u32x2*)(lds + OFF_Q + jl * LR + ho + 4 * g) =
              (u32x2){pk2(pv[0] * inv, pv[1] * inv), pk2(pv[2] * inv, pv[3] * inv)};
      }
      {   // qt 1
        float a0 = EXP2(s10[0]), a1 = EXP2(s10[1]);
        float a2 = EXP2(s10[2]), a3 = EXP2(s10[3]);
        float e0 = m0 ? EXP2(s11[0]) : 0.f, e1 = m1 ? EXP2(s11[1]) : 0.f;
        float e2 = m2 ? EXP2(s11[2]) : 0.f, e3 = m3 ? EXP2(s11[3]) : 0.f;
        float sum = ((a0 + a1) + (a2 + a3)) + ((e0 + e1) + (e2 + e3));
        sum += __shfl_xor(sum, 16, 64); sum += __shfl_xor(sum, 32, 64);
        float inv = __builtin_amdgcn_rcpf(sum);
        bf16x8 bp0 = frag((u32x4){pk2(a0, a1), pk2(a2, a3), pk2(e0, e1), pk2(e2, e3)});
        f32x4 pv = MFMA16(aw0, bp0, zf);
        if (g < 2)
          *(u32x2*)(lds + OFF_Q + (16 + jl) * LR + ho + 4 * g) =
              (u32x2){pk2(pv[0] * inv, pv[1] * inv), pk2(pv[2] * inv, pv[3] * inv)};
      }
      f32x4 s20 = MFMA16(k0, bq2, zf);
      f32x4 s21 = MFMA16(k1, bq2, zf);
      f32x4 s22 = MFMA16(k2, bq2, zf);
      f32x4 s30 = MFMA16(k0, bq3, zf);
      f32x4 s31 = MFMA16(k1, bq3, zf);
      f32x4 s32 = MFMA16(k2, bq3, zf);
      f32x4 s33 = MFMA16(k3, bq3, zf);
      {   // qt 2
        float a0 = EXP2(s20[0]), a1 = EXP2(s20[1]);
        float a2 = EXP2(s20[2]), a3 = EXP2(s20[3]);
        float c0 = EXP2(s21[0]), c1 = EXP2(s21[1]);
        float c2 = EXP2(s21[2]), c3 = EXP2(s21[3]);
        float e0 = m0 ? EXP2(s22[0]) : 0.f, e1 = m1 ? EXP2(s22[1]) : 0.f;
        float e2 = m2 ? EXP2(s22[2]) : 0.f, e3 = m3 ? EXP2(s22[3]) : 0.f;
        float sum = ((a0 + a1) + (a2 + a3)) + ((c0 + c1) + (c2 + c3))
                  + ((e0 + e1) + (e2 + e3));
        sum += __shfl_xor(sum, 16, 64); sum += __shfl_xor(sum, 32, 64);
        float inv = __builtin_amdgcn_rcpf(sum);
        bf16x8 bp0 = frag((u32x4){pk2(a0, a1), pk2(a2, a3), pk2(c0, c1), pk2(c2, c3)});
        bf16x8 bp1 = frag((u32x4){pk2(e0, e1), pk2(e2, e3), 0u, 0u});
        f32x4 pv = MFMA16(aw0, bp0, zf); pv = MFMA16(aw1, bp1, pv);
        if (g < 2)
          *(u32x2*)(lds + OFF_Q + (32 + jl) * LR + ho + 4 * g) =
              (u32x2){pk2(pv[0] * inv, pv[1] * inv), pk2(pv[2] * inv, pv[3] * inv)};
      }
      {   // qt 3
        float a0 = EXP2(s30[0]), a1 = EXP2(s30[1]);
        float a2 = EXP2(s30[2]), a3 = EXP2(s30[3]);
        float c0 = EXP2(s31[0]), c1 = EXP2(s31[1]);
        float c2 = EXP2(s31[2]), c3 = EXP2(s31[3]);
        float d0 = EXP2(s32[0]), d1 = EXP2(s32[1]);
        float d2 = EXP2(s32[2]), d3 = EXP2(s32[3]);
        float e0 = m0 ? EXP2(s33[0]) : 0.f, e1 = m1 ? EXP2(s33[1]) : 0.f;
        float e2 = m2 ? EXP2(s33[2]) : 0.f, e3 = m3 ? EXP2(s33[3]) : 0.f;
        float sum = ((a0 + a1) + (a2 + a3)) + ((c0 + c1) + (c2 + c3))
                  + ((d0 + d1) + (d2 + d3)) + ((e0 + e1) + (e2 + e3));
        sum += __shfl_xor(sum, 16, 64); sum += __shfl_xor(sum, 32, 64);
        float inv = __builtin_amdgcn_rcpf(sum);
        bf16x8 bp0 = frag((u32x4){pk2(a0, a1), pk2(a2, a3), pk2(c0, c1), pk2(c2, c3)});
        bf16x8 bp1 = frag((u32x4){pk2(d0, d1), pk2(d2, d3), pk2(e0, e1), pk2(e2, e3)});
        f32x4 pv = MFMA16(aw0, bp0, zf); pv = MFMA16(aw1, bp1, pv);
        if (g < 2)
          *(u32x2*)(lds + OFF_Q + (48 + jl) * LR + ho + 4 * g) =
              (u32x2){pk2(pv[0] * inv, pv[1] * inv), pk2(pv[2] * inv, pv[3] * inv)};
      }
    }
  }
  __syncthreads();   // barrier 2: publish attn
  bf16x8 bat0 = *(const bf16x8*)(lds + qrow + 8 * g);
  bf16x8 bat1 = *(const bf16x8*)(lds + qrow + 32 + 8 * g);

  // ---------- proj + residual; store x2 pi-packed (ONLY output of K1) ----------
  {
    unsigned short* xrow = wsm + WS_X2 + (b * 64 + (size_t)myrow) * 64;
    f32x4 x20, x21, x22, x23;
    {
      bf16x8 a0 = *(const bf16x8*)(wsm + 24 * 512 + lane * 8);
      bf16x8 a1 = *(const bf16x8*)(wsm + 25 * 512 + lane * 8);
      f32x4 acc = MFMA16(a0, bat0, zf); acc = MFMA16(a1, bat1, acc);
      x20 = xw[0] + acc + *(const f32x4*)(projb + 4 * g);
    }
    {
      bf16x8 a0 = *(const bf16x8*)(wsm + 26 * 512 + lane * 8);
      bf16x8 a1 = *(const bf16x8*)(wsm + 27 * 512 + lane * 8);
      f32x4 acc = MFMA16(a0, bat0, zf); acc = MFMA16(a1, bat1, acc);
      x21 = xw[1] + acc + *(const f32x4*)(projb + 16 + 4 * g);
    }
    *(u32x4*)(xrow + 8 * g) = (u32x4){pk2(x20[0], x20[1]), pk2(x20[2], x20[3]),
                                      pk2(x21[0], x21[1]), pk2(x21[2], x21[3])};
    {
      bf16x8 a0 = *(const bf16x8*)(wsm + 28 * 512 + lane * 8);
      bf16x8 a1 = *(const bf16x8*)(wsm + 29 * 512 + lane * 8);
      f32x4 acc = MFMA16(a0, bat0, zf); acc = MFMA16(a1, bat1, acc);
      x22 = xw[2] + acc + *(const f32x4*)(projb + 32 + 4 * g);
    }
    {
      bf16x8 a0 = *(const bf16x8*)(wsm + 30 * 512 + lane * 8);
      bf16x8 a1 = *(const bf16x8*)(wsm + 31 * 512 + lane * 8);
      f32x4 acc = MFMA16(a0, bat0, zf); acc = MFMA16(a1, bat1, acc);
      x23 = xw[3] + acc + *(const f32x4*)(projb + 48 + 4 * g);
    }
    *(u32x4*)(xrow + 32 + 8 * g) = (u32x4){pk2(x22[0], x22[1]), pk2(x22[2], x22[3]),
                                           pk2(x23[0], x23[1]), pk2(x23[2], x23[3])};
  }
}

// ========== K2: LN2 + FF GEMM -- 2 token-groups per weight read ==========
// Each wave processes 32 tokens/pass (groups A=myrow, B=myrow+64); every
// weight ds_read feeds 2 MFMAs -> weight LDS traffic per token HALVES.
__global__ __launch_bounds__(256, 2) void ff_stream(
    const unsigned short* __restrict__ wsm,
    const float* __restrict__ ln2w, const float* __restrict__ ln2b,
    const float* __restrict__ fc1b, const float* __restrict__ fc2b,
    float* __restrict__ out) {
  __shared__ __attribute__((aligned(16))) unsigned short ldsw[32768];  // 64 KB

  const int tid  = threadIdx.x;
  const int w    = tid >> 6;
  const int lane = tid & 63;
  const int g    = lane >> 4;
  const int jl   = lane & 15;
  const int myrow = 16 * w + jl;
  const f32x4 zf = {0.f, 0.f, 0.f, 0.f};

  // stage fc1+fc2 chunks (orig 32..96 -> local 0..64): 64 KB coalesced
  {
    const u32x4* src = (const u32x4*)(wsm + 16384);
    u32x4* dst = (u32x4*)ldsw;
    #pragma unroll
    for (int k = 0; k < 16; ++k) dst[k * 256 + tid] = src[k * 256 + tid];
  }
  __syncthreads();

  // LN2 scales + fc2 bias (hoisted; L2-hot)
  f32x4 lw2[4], lb2[4], fb2[4];
  #pragma unroll
  for (int mi = 0; mi < 4; ++mi) {
    lw2[mi] = *(const f32x4*)(ln2w + 16 * mi + 4 * g);
    lb2[mi] = *(const f32x4*)(ln2b + 16 * mi + 4 * g);
    fb2[mi] = *(const f32x4*)(fc2b + 16 * mi + 4 * g);
  }

  const unsigned short* x2g = wsm + WS_X2;
  const size_t tbase = (size_t)blockIdx.x * 512 + myrow;

  // prologue: preload pass-0 x2 rows for both token groups
  u32x4 vA0 = *(const u32x4*)(x2g + tbase * 64 + 8 * g);
  u32x4 vA1 = *(const u32x4*)(x2g + tbase * 64 + 32 + 8 * g);
  u32x4 vB0 = *(const u32x4*)(x2g + (tbase + 64) * 64 + 8 * g);
  u32x4 vB1 = *(const u32x4*)(x2g + (tbase + 64) * 64 + 32 + 8 * g);

  #pragma clang loop unroll(disable)
  for (int p = 0; p < 4; ++p) {
    const size_t tA = tbase + p * 128;
    const size_t tB = tA + 64;
    // unpack both groups
    f32x4 x2A[4], x2B[4];
    #pragma unroll
    for (int q = 0; q < 2; ++q) {
      u32x4 va = q ? vA1 : vA0;
      u32x4 vb = q ? vB1 : vB0;
      #pragma unroll
      for (int h = 0; h < 2; ++h) {
        x2A[2 * q + h][0] = bf2f((unsigned short)(va[2 * h] & 0xFFFF));
        x2A[2 * q + h][1] = bf2f((unsigned short)(va[2 * h] >> 16));
        x2A[2 * q + h][2] = bf2f((unsigned short)(va[2 * h + 1] & 0xFFFF));
        x2A[2 * q + h][3] = bf2f((unsigned short)(va[2 * h + 1] >> 16));
        x2B[2 * q + h][0] = bf2f((unsigned short)(vb[2 * h] & 0xFFFF));
        x2B[2 * q + h][1] = bf2f((unsigned short)(vb[2 * h] >> 16));
        x2B[2 * q + h][2] = bf2f((unsigned short)(vb[2 * h + 1] & 0xFFFF));
        x2B[2 * q + h][3] = bf2f((unsigned short)(vb[2 * h + 1] >> 16));
      }
    }
    // T14: issue next pass's x2 loads; latency hides under LN2+FF
    if (p < 3) {
      vA0 = *(const u32x4*)(x2g + (tA + 128) * 64 + 8 * g);
      vA1 = *(const u32x4*)(x2g + (tA + 128) * 64 + 32 + 8 * g);
      vB0 = *(const u32x4*)(x2g + (tB + 128) * 64 + 8 * g);
      vB1 = *(const u32x4*)(x2g + (tB + 128) * 64 + 32 + 8 * g);
    }
    sfence();

    // LN2 for both groups (independent)
    bf16x8 hcA0, hcA1, hcB0, hcB1;
    {
      float sA = 0.f, ssA = 0.f, sB = 0.f, ssB = 0.f;
      #pragma unroll
      for (int mi = 0; mi < 4; ++mi)
        #pragma unroll
        for (int r = 0; r < 4; ++r) {
          sA += x2A[mi][r]; ssA += x2A[mi][r] * x2A[mi][r];
          sB += x2B[mi][r]; ssB += x2B[mi][r] * x2B[mi][r];
        }
      sA  += __shfl_xor(sA, 16, 64);  sA  += __shfl_xor(sA, 32, 64);
      ssA += __shfl_xor(ssA, 16, 64); ssA += __shfl_xor(ssA, 32, 64);
      sB  += __shfl_xor(sB, 16, 64);  sB  += __shfl_xor(sB, 32, 64);
      ssB += __shfl_xor(ssB, 16, 64); ssB += __shfl_xor(ssB, 32, 64);
      float mA = sA * 0.015625f, mB = sB * 0.015625f;
      float rA = rsqrtf(ssA * 0.015625f - mA * mA + 1e-5f);
      float rB = rsqrtf(ssB * 0.015625f - mB * mB + 1e-5f);
      unsigned hA[8], hB[8];
      #pragma unroll
      for (int mi = 0; mi < 4; ++mi) {
        float a0 = (x2A[mi][0] - mA) * rA * lw2[mi][0] + lb2[mi][0];
        float a1 = (x2A[mi][1] - mA) * rA * lw2[mi][1] + lb2[mi][1];
        float a2 = (x2A[mi][2] - mA) * rA * lw2[mi][2] + lb2[mi][2];
        float a3 = (x2A[mi][3] - mA) * rA * lw2[mi][3] + lb2[mi][3];
        hA[2 * mi] = pk2(a0, a1); hA[2 * mi + 1] = pk2(a2, a3);
        float b0 = (x2B[mi][0] - mB) * rB * lw2[mi][0] + lb2[mi][0];
        float b1 = (x2B[mi][1] - mB) * rB * lw2[mi][1] + lb2[mi][1];
        float b2 = (x2B[mi][2] - mB) * rB * lw2[mi][2] + lb2[mi][2];
        float b3 = (x2B[mi][3] - mB) * rB * lw2[mi][3] + lb2[mi][3];
        hB[2 * mi] = pk2(b0, b1); hB[2 * mi + 1] = pk2(b2, b3);
      }
      hcA0 = frag((u32x4){hA[0], hA[1], hA[2], hA[3]});
      hcA1 = frag((u32x4){hA[4], hA[5], hA[6], hA[7]});
      hcB0 = frag((u32x4){hB[0], hB[1], hB[2], hB[3]});
      hcB1 = frag((u32x4){hB[4], hB[5], hB[6], hB[7]});
    }

    f32x4 accA[4], accB[4];
    #pragma unroll
    for (int mi = 0; mi < 4; ++mi) { accA[mi] = zf; accB[mi] = zf; }
    #pragma clang loop unroll(disable)
    for (int c = 0; c < 4; ++c) {
      const unsigned short* w1c = ldsw + (8 * c) * 512 + lane * 8;
      const unsigned short* w2c = ldsw + (32 + 2 * c) * 512 + lane * 8;
      const float* b1c = fc1b + 64 * c + 4 * g;
      unsigned frA[8], frB[8];
      #pragma unroll
      for (int ml = 0; ml < 4; ++ml) {
        bf16x8 a0 = *(const bf16x8*)(w1c + (2 * ml) * 512);
        bf16x8 a1 = *(const bf16x8*)(w1c + (2 * ml + 1) * 512);
        f32x4 bb = *(const f32x4*)(b1c + 16 * ml);
        f32x4 tA = MFMA16(a0, hcA0, zf); tA = MFMA16(a1, hcA1, tA);
        frA[2 * ml]     = pk2(fmaxf(tA[0] + bb[0], 0.f), fmaxf(tA[1] + bb[1], 0.f));
        frA[2 * ml + 1] = pk2(fmaxf(tA[2] + bb[2], 0.f), fmaxf(tA[3] + bb[3], 0.f));
        f32x4 tB = MFMA16(a0, hcB0, zf); tB = MFMA16(a1, hcB1, tB);
        frB[2 * ml]     = pk2(fmaxf(tB[0] + bb[0], 0.f), fmaxf(tB[1] + bb[1], 0.f));
        frB[2 * ml + 1] = pk2(fmaxf(tB[2] + bb[2], 0.f), fmaxf(tB[3] + bb[3], 0.f));
      }
      bf16x8 bfA0 = frag((u32x4){frA[0], frA[1], frA[2], frA[3]});
      bf16x8 bfA1 = frag((u32x4){frA[4], frA[5], frA[6], frA[7]});
      bf16x8 bfB0 = frag((u32x4){frB[0], frB[1], frB[2], frB[3]});
      bf16x8 bfB1 = frag((u32x4){frB[4], frB[5], frB[6], frB[7]});
      #pragma unroll
      for (int mi = 0; mi < 4; ++mi) {
        bf16x8 w20 = *(const bf16x8*)(w2c + (8 * mi) * 512);
        bf16x8 w21 = *(const bf16x8*)(w2c + (8 * mi + 1) * 512);
        accA[mi] = MFMA16(w20, bfA0, accA[mi]);
        accA[mi] = MFMA16(w21, bfA1, accA[mi]);
        accB[mi] = MFMA16(w20, bfB0, accB[mi]);
        accB[mi] = MFMA16(w21, bfB1, accB[mi]);
      }
    }
    float* obA = out + tA * 64;
    float* obB = out + tB * 64;
    #pragma unroll
    for (int mi = 0; mi < 4; ++mi) {
      f32x4 oA = x2A[mi] + accA[mi] + fb2[mi];
      *(f32x4*)(obA + 16 * mi + 4 * g) = oA;
      f32x4 oB = x2B[mi] + accB[mi] + fb2[mi];
      *(f32x4*)(obB + 16 * mi + 4 * g) = oB;
    }
  }
}

extern "C" void kernel_launch(void* const* d_in, const int* in_sizes, int n_in,
                              void* d_out, int out_size, void* d_ws, size_t ws_size,
                              hipStream_t stream) {
  const float* x     = (const float*)d_in[0];
  const float* ln1w  = (const float*)d_in[1];
  const float* ln1b  = (const float*)d_in[2];
  const float* wq    = (const float*)d_in[3];
  const float* wk    = (const float*)d_in[4];
  const float* wvp   = (const float*)d_in[5];
  const float* projw = (const float*)d_in[6];
  const float* projb = (const float*)d_in[7];
  const float* ln2w  = (const float*)d_in[8];
  const float* ln2b  = (const float*)d_in[9];
  const float* fc1w  = (const float*)d_in[10];
  const float* fc1b  = (const float*)d_in[11];
  const float* fc2w  = (const float*)d_in[12];
  const float* fc2b  = (const float*)d_in[13];
  unsigned short* ws = (unsigned short*)d_ws;   // needs ~33.7 MB
  float* out = (float*)d_out;

  prep_weights<<<dim3(24), dim3(256), 0, stream>>>(wq, wk, wvp, projw, fc1w, fc2w, ws);

  int nblk = in_sizes[0] / 4096;
  block_attn<<<dim3(nblk), dim3(256), 0, stream>>>(
      x, ln1w, ln1b, projb, ws);

  int nblk2 = (nblk * 64) / 512;   // 512 tokens per FF block (2 groups x 4 passes)
  ff_stream<<<dim3(nblk2), dim3(256), 0, stream>>>(ws, ln2w, ln2b, fc1b, fc2b, out);
}